// Round 2
// baseline (6431.004 us; speedup 1.0000x reference)
//
#include <hip/hip_runtime.h>
#include <hip/hip_bf16.h>
#include <math.h>

// Per-batch processing: all stages are batch-independent, so we loop b=0..3
// reusing one ~78MB set of per-batch buffers (previous full-batch layout
// needed 311MB of d_ws and crashed -- presumed workspace overflow).

#define HH 256
#define WWI 256
#define HW 65536
#define CH 31
#define CIN2 62
#define CM 3
#define CE 128
#define REGC 288
#define C1S 1e-4f
#define C2S 9e-4f

typedef unsigned short u16;
typedef unsigned int u32;

__device__ __forceinline__ float blo(u32 u){ return __uint_as_float(u << 16); }
__device__ __forceinline__ float bhi(u32 u){ return __uint_as_float(u & 0xffff0000u); }
__device__ __forceinline__ float b1f(u16 u){ return __uint_as_float(((u32)u) << 16); }
__device__ __forceinline__ u16 f2b(float f){
    u32 u = __float_as_uint(f);
    u32 r = (u + 0x7fffu + ((u >> 16) & 1u)) >> 16;
    return (u16)r;
}

// ---------------- 1) conv_half (one batch): (62,H,W) f32 -> x31 NHWC f32 [pix][32]
__global__ void k_conv_half(const float* __restrict__ x, const float* __restrict__ w,
                            const float* __restrict__ bias, float* __restrict__ x31){
    __shared__ float sw[CH*CIN2];
    __shared__ float sb[CH+1];
    for(int i=threadIdx.x;i<CH*CIN2;i+=256) sw[i]=w[i];
    for(int i=threadIdx.x;i<CH;i+=256) sb[i]=bias[i];
    __syncthreads();
    int pix = blockIdx.x*256 + threadIdx.x;
    if(pix>=HW) return;
    float acc[CH];
    #pragma unroll
    for(int c=0;c<CH;c++) acc[c]=sb[c];
    for(int ci=0;ci<CIN2;ci++){
        float xv = x[(size_t)ci*HW + pix];
        #pragma unroll
        for(int c=0;c<CH;c++) acc[c] += sw[c*CIN2+ci]*xv;
    }
    float* o = x31 + (size_t)pix*32;
    #pragma unroll
    for(int c=0;c<CH;c++) o[c]=acc[c];
    o[31]=0.f;
}

// ---------------- 2) project: xp = clip(SRF @ x31, -1, 1), layout [3][HW] --------
__global__ void k_project(const float* __restrict__ x31, const float* __restrict__ srf,
                          float* __restrict__ xp){
    __shared__ float s[CM*CH];
    for(int i=threadIdx.x;i<CM*CH;i+=256) s[i]=srf[i];
    __syncthreads();
    int pix = blockIdx.x*256 + threadIdx.x;
    if(pix>=HW) return;
    const float* xr = x31 + (size_t)pix*32;
    #pragma unroll
    for(int m=0;m<CM;m++){
        float acc=0.f;
        #pragma unroll
        for(int c=0;c<CH;c++) acc += s[m*CH+c]*xr[c];
        acc = fminf(fmaxf(acc,-1.f),1.f);
        xp[(size_t)m*HW + pix] = acc;
    }
}

// ---------------- 3) stats: mean/std(ddof=1); planes 0..2 = xp, 3..5 = y ---------
__global__ void k_stats(const float* __restrict__ xp, const float* __restrict__ y,
                        float* __restrict__ stats){
    int p = blockIdx.x;
    const float* src = (p<3) ? (xp + (size_t)p*HW) : (y + (size_t)(p-3)*HW);
    float s=0.f, ss=0.f;
    for(int i=threadIdx.x;i<HW;i+=256){ float v=src[i]; s+=v; ss+=v*v; }
    __shared__ float rs[256], rss[256];
    rs[threadIdx.x]=s; rss[threadIdx.x]=ss;
    __syncthreads();
    for(int st=128;st>0;st>>=1){
        if(threadIdx.x<st){ rs[threadIdx.x]+=rs[threadIdx.x+st]; rss[threadIdx.x]+=rss[threadIdx.x+st]; }
        __syncthreads();
    }
    if(threadIdx.x==0){
        float mean = rs[0]/(float)HW;
        float var = (rss[0] - rs[0]*rs[0]/(float)HW) / (float)(HW-1);
        stats[p*2] = mean;
        stats[p*2+1] = sqrtf(fmaxf(var,0.f));
    }
}

// ---------------- 4) align ---------------------------------------------------------
__global__ void k_align(const float* __restrict__ xp, const float* __restrict__ stats,
                        float* __restrict__ xa){
    int i = blockIdx.x*256 + threadIdx.x;
    if(i>=3*HW) return;
    int plane = i>>16;
    float sm = stats[plane*2], ssd = stats[plane*2+1];
    float rm = stats[(plane+3)*2], rsd = stats[(plane+3)*2+1];
    float v = (xp[i]-sm)/(ssd+1e-6f)*rsd + rm;
    xa[i] = fminf(fmaxf(v,-1.f),1.f);
}

// ---------------- 5) ssim horizontal gaussian pass ---------------------------------
__global__ void k_ssim_h(const float* __restrict__ xa, const float* __restrict__ y,
                         float* __restrict__ tmp){
    int i = blockIdx.x*256 + threadIdx.x;
    if(i>=3*HW) return;
    int plane = i>>16, hw = i&65535, h = hw>>8, w = hw&255;
    float g[9]; float gs=0.f;
    #pragma unroll
    for(int t=0;t<9;t++){ float cc=(float)(t-4); g[t]=expf(-cc*cc/4.5f); gs+=g[t]; }
    float inv = 1.f/gs;
    float s0=0,s1=0,s2=0,s3=0,s4=0;
    const float* xr = xa + (size_t)plane*HW + (size_t)h*256;
    const float* yr = y  + (size_t)plane*HW + (size_t)h*256;
    #pragma unroll
    for(int t=0;t<9;t++){
        int wc = w + t - 4;
        if(wc>=0 && wc<256){
            float gg = g[t]*inv;
            float a = xr[wc], b = yr[wc];
            s0+=gg*a; s1+=gg*b; s2+=gg*a*a; s3+=gg*b*b; s4+=gg*a*b;
        }
    }
    size_t base = (size_t)plane*5*HW + hw;
    tmp[base]=s0; tmp[base+HW]=s1; tmp[base+2*(size_t)HW]=s2; tmp[base+3*(size_t)HW]=s3; tmp[base+4*(size_t)HW]=s4;
}

// ---------------- 6) ssim vertical pass + difficulty -> diff, regin ch281 ---------
__global__ void k_ssim_v(const float* __restrict__ tmp, float* __restrict__ diff,
                         u16* __restrict__ regin){
    int pix = blockIdx.x*256 + threadIdx.x;
    if(pix>=HW) return;
    int h = pix>>8, w = pix&255;
    float g[9]; float gs=0.f;
    #pragma unroll
    for(int t=0;t<9;t++){ float cc=(float)(t-4); g[t]=expf(-cc*cc/4.5f); gs+=g[t]; }
    float inv = 1.f/gs;
    float msum = 0.f;
    for(int m=0;m<3;m++){
        float v0=0,v1=0,v2=0,v3=0,v4=0;
        #pragma unroll
        for(int t=0;t<9;t++){
            int hc = h + t - 4;
            if(hc>=0 && hc<256){
                float gg = g[t]*inv;
                size_t base = (size_t)m*5*HW + (size_t)hc*256 + w;
                v0+=gg*tmp[base]; v1+=gg*tmp[base+HW]; v2+=gg*tmp[base+2*(size_t)HW];
                v3+=gg*tmp[base+3*(size_t)HW]; v4+=gg*tmp[base+4*(size_t)HW];
            }
        }
        float mu1=v0, mu2=v1;
        float mu1s=mu1*mu1, mu2s=mu2*mu2, mu12=mu1*mu2;
        float sg1=v2-mu1s, sg2=v3-mu2s, sg12=v4-mu12;
        float num=(2.f*mu12+C1S)*(2.f*sg12+C2S);
        float den=(mu1s+mu2s+C1S)*(sg1+sg2+C2S);
        msum += num/den;
    }
    float ss = msum*(1.f/3.f);
    float d = fminf(fmaxf((1.f-ss)*0.5f,0.f),1.f);
    diff[pix] = d;
    regin[(size_t)pix*REGC + 281] = f2b(d);
}

// ---------------- 7) q,k 1x1 convs -> regin bf16 -----------------------------------
__global__ void k_qk(const float* __restrict__ x31, const float* __restrict__ y,
                     const float* __restrict__ qw, const float* __restrict__ qb,
                     const float* __restrict__ kw, const float* __restrict__ kb,
                     u16* __restrict__ regin){
    __shared__ float sqw[CE*CH];
    __shared__ float skw[CE*CM];
    __shared__ float sqb[CE], skb[CE];
    for(int i=threadIdx.x;i<CE*CH;i+=128) sqw[i]=qw[i];
    for(int i=threadIdx.x;i<CE*CM;i+=128) skw[i]=kw[i];
    if(threadIdx.x<CE){ sqb[threadIdx.x]=qb[threadIdx.x]; skb[threadIdx.x]=kb[threadIdx.x]; }
    __syncthreads();
    int co = threadIdx.x;
    int p0 = blockIdx.x*4;
    for(int pp=0;pp<4;pp++){
        int pix = p0+pp;
        const float* xr = x31 + (size_t)pix*32;
        float acc = sqb[co];
        #pragma unroll
        for(int c=0;c<CH;c++) acc += sqw[co*CH+c]*xr[c];
        regin[(size_t)pix*REGC + co] = f2b(acc);
        float ack = skb[co];
        #pragma unroll
        for(int c=0;c<CM;c++) ack += skw[co*CM+c]*y[(size_t)c*HW + pix];
        regin[(size_t)pix*REGC + 128 + co] = f2b(ack);
        if(co<6) regin[(size_t)pix*REGC + 282 + co] = 0;  // zero channel pad
    }
}

// ---------------- 8) inverse l2 norms of q,k per pixel -----------------------------
__global__ void k_norms(const u16* __restrict__ regin, float* __restrict__ qinv,
                        float* __restrict__ kinv){
    int wid = threadIdx.x>>6, lane = threadIdx.x&63;
    int pix = blockIdx.x*4 + wid;
    const u32* qp = (const u32*)(regin + (size_t)pix*REGC);
    u32 qu = qp[lane];
    float q0=blo(qu), q1=bhi(qu);
    float s = q0*q0 + q1*q1;
    #pragma unroll
    for(int t=1;t<64;t<<=1) s += __shfl_xor(s,t);
    if(lane==0) qinv[pix] = 1.f/fmaxf(sqrtf(s),1e-12f);
    const u32* kp = (const u32*)(regin + (size_t)pix*REGC + 128);
    u32 ku = kp[lane];
    float k0=blo(ku), k1=bhi(ku);
    float sk = k0*k0 + k1*k1;
    #pragma unroll
    for(int t=1;t<64;t<<=1) sk += __shfl_xor(sk,t);
    if(lane==0) kinv[pix] = 1.f/fmaxf(sqrtf(sk),1e-12f);
}

// ---------------- 9) correlation volume (25 offsets, edge clamp) -> regin ----------
__global__ void k_corr(const u16* __restrict__ regin, const float* __restrict__ qinv,
                       const float* __restrict__ kinv, u16* __restrict__ regout){
    int wid = threadIdx.x>>6, lane = threadIdx.x&63;
    int pix = blockIdx.x*4 + wid;
    int h = pix>>8, w = pix&255;
    const u32* qp = (const u32*)(regin + (size_t)pix*REGC);
    u32 qu = qp[lane];
    float q0=blo(qu), q1=bhi(qu);
    float qn = qinv[pix];
    float res = 0.f;
    #pragma unroll
    for(int dy=-2;dy<=2;dy++){
        int hc = min(max(h+dy,0),255);
        #pragma unroll
        for(int dx=-2;dx<=2;dx++){
            int wc = min(max(w+dx,0),255);
            int npix = (hc<<8)+wc;
            const u32* kp = (const u32*)(regin + (size_t)npix*REGC + 128);
            u32 ku = kp[lane];
            float p = q0*blo(ku) + q1*bhi(ku);
            #pragma unroll
            for(int s=1;s<64;s<<=1) p += __shfl_xor(p,s);
            float cv = p*qn*kinv[npix];
            int o = (dy+2)*5 + (dx+2);
            if(lane==o) res = cv;
        }
    }
    if(lane<25) regout[(size_t)pix*REGC + 256 + lane] = f2b(res);
}

// ---------------- 10) weight rearrange: OIHW f32 -> [tap][ci][co] bf16 (once) ------
__global__ void k_wre(const float* __restrict__ w1, const float* __restrict__ w2,
                      u16* __restrict__ w1r, u16* __restrict__ w2r){
    int i = blockIdx.x*256 + threadIdx.x;
    if(i < 9*REGC*128){
        int co = i & 127; int rest = i>>7;
        int c = rest % REGC; int tap = rest / REGC;
        float v = 0.f;
        if(c < 282) v = w1[((size_t)co*282 + c)*9 + tap];
        w1r[i] = f2b(v);
    }
    if(i < 9*128*64){
        int co = i & 63; int rest = i>>6;
        int c = rest & 127; int tap = rest>>7;
        w2r[i] = f2b(w2[((size_t)co*128 + c)*9 + tap]);
    }
}

// ---------------- 11) r1: 3x3 conv 288->128 + leaky_relu(0.2) ----------------------
__global__ __launch_bounds__(256) void k_r1(const u16* __restrict__ regin,
                                            const u16* __restrict__ w1r,
                                            const float* __restrict__ bias1,
                                            u16* __restrict__ h1){
    __shared__ u16 sIn[REGC*82];   // [c][4 rows][20 cols], c-stride 82
    int bid = blockIdx.x;
    int tx = bid & 15, ty = bid>>4;           // ty 0..127
    int h0 = ty*2, w0 = tx*16;
    for(int r=0;r<4;r++){
        int ih = h0-1+r;
        bool vr = ((unsigned)ih < 256u);
        for(int i=threadIdx.x;i<18*REGC;i+=256){
            int col = i/REGC;
            int c = i - col*REGC;
            int iw = w0-1+col;
            u16 v = 0;
            if(vr && (unsigned)iw<256u)
                v = regin[((size_t)((ih<<8)+iw))*REGC + c];
            sIn[c*82 + r*20 + col] = v;
        }
    }
    __syncthreads();
    int co = threadIdx.x & 127, pg = threadIdx.x >> 7;
    float acc[16];
    float bs = bias1[co];
    #pragma unroll
    for(int p=0;p<16;p++) acc[p]=bs;
    const u32* s32 = (const u32*)sIn;
    #pragma unroll 2
    for(int c=0;c<REGC;c++){
        #pragma unroll
        for(int ky=0;ky<3;ky++){
            int row = pg+ky;
            int rb = 41*c + 10*row;
            float v[18];
            #pragma unroll
            for(int j=0;j<9;j++){ u32 u = s32[rb+j]; v[2*j]=blo(u); v[2*j+1]=bhi(u); }
            int wb = (ky*3*REGC + c)*128 + co;
            float wf0 = b1f(w1r[wb]);
            float wf1 = b1f(w1r[wb + REGC*128]);
            float wf2 = b1f(w1r[wb + 2*REGC*128]);
            #pragma unroll
            for(int p=0;p<16;p++) acc[p] += wf0*v[p] + wf1*v[p+1] + wf2*v[p+2];
        }
    }
    int oh = h0+pg;
    size_t ob = ((size_t)((oh<<8)+w0))*128 + co;
    #pragma unroll
    for(int p=0;p<16;p++){
        float a = acc[p];
        a = (a>0.f) ? a : 0.2f*a;
        h1[ob + (size_t)p*128] = f2b(a);
    }
}

// ---------------- 12) r2: 3x3 conv 128->64 + leaky_relu(0.2) -----------------------
__global__ __launch_bounds__(256) void k_r2(const u16* __restrict__ h1,
                                            const u16* __restrict__ w2r,
                                            const float* __restrict__ bias2,
                                            u16* __restrict__ h2){
    __shared__ u16 sIn[128*122];   // [c][6 rows][20 cols], c-stride 122
    int bid = blockIdx.x;
    int tx = bid & 15, ty = bid>>4;           // ty 0..63
    int h0 = ty*4, w0 = tx*16;
    for(int r=0;r<6;r++){
        int ih = h0-1+r;
        bool vr = ((unsigned)ih < 256u);
        for(int i=threadIdx.x;i<18*128;i+=256){
            int col = i>>7;
            int c = i & 127;
            int iw = w0-1+col;
            u16 v = 0;
            if(vr && (unsigned)iw<256u)
                v = h1[((size_t)((ih<<8)+iw))*128 + c];
            sIn[c*122 + r*20 + col] = v;
        }
    }
    __syncthreads();
    int co = threadIdx.x & 63, pg = threadIdx.x >> 6;
    float acc[16];
    float bs = bias2[co];
    #pragma unroll
    for(int p=0;p<16;p++) acc[p]=bs;
    const u32* s32 = (const u32*)sIn;
    #pragma unroll 2
    for(int c=0;c<128;c++){
        #pragma unroll
        for(int ky=0;ky<3;ky++){
            int row = pg+ky;
            int rb = 61*c + 10*row;
            float v[18];
            #pragma unroll
            for(int j=0;j<9;j++){ u32 u = s32[rb+j]; v[2*j]=blo(u); v[2*j+1]=bhi(u); }
            int wb = (ky*3*128 + c)*64 + co;
            float wf0 = b1f(w2r[wb]);
            float wf1 = b1f(w2r[wb + 128*64]);
            float wf2 = b1f(w2r[wb + 2*128*64]);
            #pragma unroll
            for(int p=0;p<16;p++) acc[p] += wf0*v[p] + wf1*v[p+1] + wf2*v[p+2];
        }
    }
    int oh = h0+pg;
    size_t ob = ((size_t)((oh<<8)+w0))*64 + co;
    #pragma unroll
    for(int p=0;p<16;p++){
        float a = acc[p];
        a = (a>0.f) ? a : 0.2f*a;
        h2[ob + (size_t)p*64] = f2b(a);
    }
}

// ---------------- 13) flow (1x1 conv + tanh) + bilinear warp -----------------------
__device__ __forceinline__ float reflectc(float coord, float size){
    float c = fabsf(coord + 0.5f);
    float extra = fmodf(c, size);
    float flips = floorf(c/size);
    float fo = fmodf(flips, 2.0f);
    float r = (fo == 0.0f) ? (extra - 0.5f) : (size - extra - 0.5f);
    return fminf(fmaxf(r, 0.0f), size - 1.0f);
}

__global__ void k_flowwarp(const u16* __restrict__ h2, const float* __restrict__ w3,
                           const float* __restrict__ b3, const float* __restrict__ diff,
                           const float* __restrict__ x31, float* __restrict__ out){
    __shared__ float sw[130];
    for(int i=threadIdx.x;i<128;i+=256) sw[i]=w3[i];
    if(threadIdx.x<2) sw[128+threadIdx.x]=b3[threadIdx.x];
    __syncthreads();
    int pix = blockIdx.x*256 + threadIdx.x;
    if(pix>=HW) return;
    int h = pix>>8, w = pix&255;
    const uint4* h4 = (const uint4*)(h2 + (size_t)pix*64);
    float f0 = sw[128], f1 = sw[129];
    #pragma unroll
    for(int cc=0;cc<8;cc++){
        uint4 u = h4[cc];
        float vv[8] = {blo(u.x),bhi(u.x),blo(u.y),bhi(u.y),blo(u.z),bhi(u.z),blo(u.w),bhi(u.w)};
        #pragma unroll
        for(int j=0;j<8;j++){ int c = cc*8+j; f0 += sw[c]*vv[j]; f1 += sw[64+c]*vv[j]; }
    }
    float d = diff[pix];
    f0 = tanhf(f0)*2.0f*d;
    f1 = tanhf(f1)*2.0f*d;
    float ix = reflectc((float)w + f0, 256.f);
    float iy = reflectc((float)h + f1, 256.f);
    float x0 = floorf(ix), y0 = floorf(iy);
    float wx = ix-x0, wy = iy-y0;
    int x0i = min(max((int)x0,0),255);
    int x1i = min(x0i+1,255);
    int y0i = min(max((int)y0,0),255);
    int y1i = min(y0i+1,255);
    const float* p00 = x31 + ((size_t)((y0i<<8)+x0i))*32;
    const float* p01 = x31 + ((size_t)((y0i<<8)+x1i))*32;
    const float* p10 = x31 + ((size_t)((y1i<<8)+x0i))*32;
    const float* p11 = x31 + ((size_t)((y1i<<8)+x1i))*32;
    float w00=(1.f-wy)*(1.f-wx), w01=(1.f-wy)*wx, w10=wy*(1.f-wx), w11=wy*wx;
    float* ob = out + pix;
    #pragma unroll
    for(int c=0;c<CH;c++){
        ob[(size_t)c*HW] = w00*p00[c] + w01*p01[c] + w10*p10[c] + w11*p11[c];
    }
}

extern "C" void kernel_launch(void* const* d_in, const int* in_sizes, int n_in,
                              void* d_out, int out_size, void* d_ws, size_t ws_size,
                              hipStream_t stream) {
    const float* x    = (const float*)d_in[0];
    const float* y    = (const float*)d_in[1];
    const float* srf  = (const float*)d_in[2];
    const float* chw  = (const float*)d_in[3];
    const float* chb  = (const float*)d_in[4];
    const float* qw   = (const float*)d_in[5];
    const float* qb   = (const float*)d_in[6];
    const float* kw   = (const float*)d_in[7];
    const float* kb   = (const float*)d_in[8];
    const float* w1   = (const float*)d_in[9];
    const float* b1p  = (const float*)d_in[10];
    const float* w2   = (const float*)d_in[11];
    const float* b2p  = (const float*)d_in[12];
    const float* w3   = (const float*)d_in[13];
    const float* b3p  = (const float*)d_in[14];

    // Per-batch workspace (reused across b=0..3): ~78 MB total.
    char* ws = (char*)d_ws;
    size_t o = 0;
    float* x31   = (float*)(ws+o); o += (size_t)HW*32*4;       //  8.4 MB
    float* xp    = (float*)(ws+o); o += (size_t)3*HW*4;        //  0.8 MB
    float* xa    = (float*)(ws+o); o += (size_t)3*HW*4;        //  0.8 MB
    float* stats = (float*)(ws+o); o += 256;
    float* tmp   = (float*)(ws+o); o += (size_t)15*HW*4;       //  3.9 MB
    float* diff  = (float*)(ws+o); o += (size_t)HW*4;          //  0.3 MB
    float* qinv  = (float*)(ws+o); o += (size_t)HW*4;
    float* kinv  = (float*)(ws+o); o += (size_t)HW*4;
    u16* regin   = (u16*)(ws+o);   o += (size_t)HW*REGC*2;     // 37.7 MB
    u16* h1      = (u16*)(ws+o);   o += (size_t)HW*128*2;      // 16.8 MB
    u16* h2      = (u16*)(ws+o);   o += (size_t)HW*64*2;       //  8.4 MB
    u16* w1r     = (u16*)(ws+o);   o += (size_t)9*REGC*128*2;  //  0.7 MB
    u16* w2r     = (u16*)(ws+o);   o += (size_t)9*128*64*2;    //  0.1 MB

    k_wre<<<1296, 256, 0, stream>>>(w1, w2, w1r, w2r);

    for(int b=0;b<4;b++){
        const float* xb  = x + (size_t)b*CIN2*HW;
        const float* yb  = y + (size_t)b*CM*HW;
        float* outb      = (float*)d_out + (size_t)b*CH*HW;

        k_conv_half<<<256,  256, 0, stream>>>(xb, chw, chb, x31);
        k_project  <<<256,  256, 0, stream>>>(x31, srf, xp);
        k_stats    <<<6,    256, 0, stream>>>(xp, yb, stats);
        k_align    <<<768,  256, 0, stream>>>(xp, stats, xa);
        k_ssim_h   <<<768,  256, 0, stream>>>(xa, yb, tmp);
        k_ssim_v   <<<256,  256, 0, stream>>>(tmp, diff, regin);
        k_qk       <<<16384,128, 0, stream>>>(x31, yb, qw, qb, kw, kb, regin);
        k_norms    <<<16384,256, 0, stream>>>(regin, qinv, kinv);
        k_corr     <<<16384,256, 0, stream>>>(regin, qinv, kinv, regin);
        k_r1       <<<2048, 256, 0, stream>>>(regin, w1r, b1p, h1);
        k_r2       <<<1024, 256, 0, stream>>>(h1, w2r, b2p, h2);
        k_flowwarp <<<256,  256, 0, stream>>>(h2, w3, b3p, diff, x31, outb);
    }
}

// Round 3
// 1754.161 us; speedup vs baseline: 3.6661x; 3.6661x over previous
//
#include <hip/hip_runtime.h>
#include <hip/hip_bf16.h>
#include <math.h>

// Per-batch pipeline; r1/r2 are now MFMA implicit-GEMM conv kernels.

#define HH 256
#define WWI 256
#define HW 65536
#define CH 31
#define CIN2 62
#define CM 3
#define CE 128
#define REGC 288
#define C1S 1e-4f
#define C2S 9e-4f

typedef unsigned short u16;
typedef unsigned int u32;
typedef short bf16x8 __attribute__((ext_vector_type(8)));   // 8 bf16 in 4 VGPRs
typedef float f32x4 __attribute__((ext_vector_type(4)));

__device__ __forceinline__ float blo(u32 u){ return __uint_as_float(u << 16); }
__device__ __forceinline__ float bhi(u32 u){ return __uint_as_float(u & 0xffff0000u); }
__device__ __forceinline__ float b1f(u16 u){ return __uint_as_float(((u32)u) << 16); }
__device__ __forceinline__ u16 f2b(float f){
    u32 u = __float_as_uint(f);
    u32 r = (u + 0x7fffu + ((u >> 16) & 1u)) >> 16;
    return (u16)r;
}
__device__ __forceinline__ f32x4 mfma16(bf16x8 a, bf16x8 b, f32x4 c){
    return __builtin_amdgcn_mfma_f32_16x16x32_bf16(a, b, c, 0, 0, 0);
}

// ---------------- 1) conv_half (one batch): (62,H,W) f32 -> x31 NHWC f32 [pix][32]
__global__ void k_conv_half(const float* __restrict__ x, const float* __restrict__ w,
                            const float* __restrict__ bias, float* __restrict__ x31){
    __shared__ float sw[CH*CIN2];
    __shared__ float sb[CH+1];
    for(int i=threadIdx.x;i<CH*CIN2;i+=256) sw[i]=w[i];
    for(int i=threadIdx.x;i<CH;i+=256) sb[i]=bias[i];
    __syncthreads();
    int pix = blockIdx.x*256 + threadIdx.x;
    if(pix>=HW) return;
    float acc[CH];
    #pragma unroll
    for(int c=0;c<CH;c++) acc[c]=sb[c];
    for(int ci=0;ci<CIN2;ci++){
        float xv = x[(size_t)ci*HW + pix];
        #pragma unroll
        for(int c=0;c<CH;c++) acc[c] += sw[c*CIN2+ci]*xv;
    }
    float* o = x31 + (size_t)pix*32;
    #pragma unroll
    for(int c=0;c<CH;c++) o[c]=acc[c];
    o[31]=0.f;
}

// ---------------- 2) project: xp = clip(SRF @ x31, -1, 1), layout [3][HW] --------
__global__ void k_project(const float* __restrict__ x31, const float* __restrict__ srf,
                          float* __restrict__ xp){
    __shared__ float s[CM*CH];
    for(int i=threadIdx.x;i<CM*CH;i+=256) s[i]=srf[i];
    __syncthreads();
    int pix = blockIdx.x*256 + threadIdx.x;
    if(pix>=HW) return;
    const float* xr = x31 + (size_t)pix*32;
    #pragma unroll
    for(int m=0;m<CM;m++){
        float acc=0.f;
        #pragma unroll
        for(int c=0;c<CH;c++) acc += s[m*CH+c]*xr[c];
        acc = fminf(fmaxf(acc,-1.f),1.f);
        xp[(size_t)m*HW + pix] = acc;
    }
}

// ---------------- 3) stats: mean/std(ddof=1); planes 0..2 = xp, 3..5 = y ---------
__global__ void k_stats(const float* __restrict__ xp, const float* __restrict__ y,
                        float* __restrict__ stats){
    int p = blockIdx.x;
    const float* src = (p<3) ? (xp + (size_t)p*HW) : (y + (size_t)(p-3)*HW);
    float s=0.f, ss=0.f;
    for(int i=threadIdx.x;i<HW;i+=256){ float v=src[i]; s+=v; ss+=v*v; }
    __shared__ float rs[256], rss[256];
    rs[threadIdx.x]=s; rss[threadIdx.x]=ss;
    __syncthreads();
    for(int st=128;st>0;st>>=1){
        if(threadIdx.x<st){ rs[threadIdx.x]+=rs[threadIdx.x+st]; rss[threadIdx.x]+=rss[threadIdx.x+st]; }
        __syncthreads();
    }
    if(threadIdx.x==0){
        float mean = rs[0]/(float)HW;
        float var = (rss[0] - rs[0]*rs[0]/(float)HW) / (float)(HW-1);
        stats[p*2] = mean;
        stats[p*2+1] = sqrtf(fmaxf(var,0.f));
    }
}

// ---------------- 4) align ---------------------------------------------------------
__global__ void k_align(const float* __restrict__ xp, const float* __restrict__ stats,
                        float* __restrict__ xa){
    int i = blockIdx.x*256 + threadIdx.x;
    if(i>=3*HW) return;
    int plane = i>>16;
    float sm = stats[plane*2], ssd = stats[plane*2+1];
    float rm = stats[(plane+3)*2], rsd = stats[(plane+3)*2+1];
    float v = (xp[i]-sm)/(ssd+1e-6f)*rsd + rm;
    xa[i] = fminf(fmaxf(v,-1.f),1.f);
}

// ---------------- 5) ssim horizontal gaussian pass ---------------------------------
__global__ void k_ssim_h(const float* __restrict__ xa, const float* __restrict__ y,
                         float* __restrict__ tmp){
    int i = blockIdx.x*256 + threadIdx.x;
    if(i>=3*HW) return;
    int plane = i>>16, hw = i&65535, h = hw>>8, w = hw&255;
    float g[9]; float gs=0.f;
    #pragma unroll
    for(int t=0;t<9;t++){ float cc=(float)(t-4); g[t]=expf(-cc*cc/4.5f); gs+=g[t]; }
    float inv = 1.f/gs;
    float s0=0,s1=0,s2=0,s3=0,s4=0;
    const float* xr = xa + (size_t)plane*HW + (size_t)h*256;
    const float* yr = y  + (size_t)plane*HW + (size_t)h*256;
    #pragma unroll
    for(int t=0;t<9;t++){
        int wc = w + t - 4;
        if(wc>=0 && wc<256){
            float gg = g[t]*inv;
            float a = xr[wc], b = yr[wc];
            s0+=gg*a; s1+=gg*b; s2+=gg*a*a; s3+=gg*b*b; s4+=gg*a*b;
        }
    }
    size_t base = (size_t)plane*5*HW + hw;
    tmp[base]=s0; tmp[base+HW]=s1; tmp[base+2*(size_t)HW]=s2; tmp[base+3*(size_t)HW]=s3; tmp[base+4*(size_t)HW]=s4;
}

// ---------------- 6) ssim vertical pass + difficulty -> diff, regin ch281 ---------
__global__ void k_ssim_v(const float* __restrict__ tmp, float* __restrict__ diff,
                         u16* __restrict__ regin){
    int pix = blockIdx.x*256 + threadIdx.x;
    if(pix>=HW) return;
    int h = pix>>8, w = pix&255;
    float g[9]; float gs=0.f;
    #pragma unroll
    for(int t=0;t<9;t++){ float cc=(float)(t-4); g[t]=expf(-cc*cc/4.5f); gs+=g[t]; }
    float inv = 1.f/gs;
    float msum = 0.f;
    for(int m=0;m<3;m++){
        float v0=0,v1=0,v2=0,v3=0,v4=0;
        #pragma unroll
        for(int t=0;t<9;t++){
            int hc = h + t - 4;
            if(hc>=0 && hc<256){
                float gg = g[t]*inv;
                size_t base = (size_t)m*5*HW + (size_t)hc*256 + w;
                v0+=gg*tmp[base]; v1+=gg*tmp[base+HW]; v2+=gg*tmp[base+2*(size_t)HW];
                v3+=gg*tmp[base+3*(size_t)HW]; v4+=gg*tmp[base+4*(size_t)HW];
            }
        }
        float mu1=v0, mu2=v1;
        float mu1s=mu1*mu1, mu2s=mu2*mu2, mu12=mu1*mu2;
        float sg1=v2-mu1s, sg2=v3-mu2s, sg12=v4-mu12;
        float num=(2.f*mu12+C1S)*(2.f*sg12+C2S);
        float den=(mu1s+mu2s+C1S)*(sg1+sg2+C2S);
        msum += num/den;
    }
    float ss = msum*(1.f/3.f);
    float d = fminf(fmaxf((1.f-ss)*0.5f,0.f),1.f);
    diff[pix] = d;
    regin[(size_t)pix*REGC + 281] = f2b(d);
}

// ---------------- 7) q,k 1x1 convs -> regin bf16 -----------------------------------
__global__ void k_qk(const float* __restrict__ x31, const float* __restrict__ y,
                     const float* __restrict__ qw, const float* __restrict__ qb,
                     const float* __restrict__ kw, const float* __restrict__ kb,
                     u16* __restrict__ regin){
    __shared__ float sqw[CE*CH];
    __shared__ float skw[CE*CM];
    __shared__ float sqb[CE], skb[CE];
    for(int i=threadIdx.x;i<CE*CH;i+=128) sqw[i]=qw[i];
    for(int i=threadIdx.x;i<CE*CM;i+=128) skw[i]=kw[i];
    if(threadIdx.x<CE){ sqb[threadIdx.x]=qb[threadIdx.x]; skb[threadIdx.x]=kb[threadIdx.x]; }
    __syncthreads();
    int co = threadIdx.x;
    int p0 = blockIdx.x*4;
    for(int pp=0;pp<4;pp++){
        int pix = p0+pp;
        const float* xr = x31 + (size_t)pix*32;
        float acc = sqb[co];
        #pragma unroll
        for(int c=0;c<CH;c++) acc += sqw[co*CH+c]*xr[c];
        regin[(size_t)pix*REGC + co] = f2b(acc);
        float ack = skb[co];
        #pragma unroll
        for(int c=0;c<CM;c++) ack += skw[co*CM+c]*y[(size_t)c*HW + pix];
        regin[(size_t)pix*REGC + 128 + co] = f2b(ack);
        if(co<6) regin[(size_t)pix*REGC + 282 + co] = 0;  // zero channel pad
    }
}

// ---------------- 8) inverse l2 norms of q,k per pixel -----------------------------
__global__ void k_norms(const u16* __restrict__ regin, float* __restrict__ qinv,
                        float* __restrict__ kinv){
    int wid = threadIdx.x>>6, lane = threadIdx.x&63;
    int pix = blockIdx.x*4 + wid;
    const u32* qp = (const u32*)(regin + (size_t)pix*REGC);
    u32 qu = qp[lane];
    float q0=blo(qu), q1=bhi(qu);
    float s = q0*q0 + q1*q1;
    #pragma unroll
    for(int t=1;t<64;t<<=1) s += __shfl_xor(s,t);
    if(lane==0) qinv[pix] = 1.f/fmaxf(sqrtf(s),1e-12f);
    const u32* kp = (const u32*)(regin + (size_t)pix*REGC + 128);
    u32 ku = kp[lane];
    float k0=blo(ku), k1=bhi(ku);
    float sk = k0*k0 + k1*k1;
    #pragma unroll
    for(int t=1;t<64;t<<=1) sk += __shfl_xor(sk,t);
    if(lane==0) kinv[pix] = 1.f/fmaxf(sqrtf(sk),1e-12f);
}

// ---------------- 9) correlation volume (25 offsets, edge clamp) -> regin ----------
__global__ void k_corr(const u16* __restrict__ regin, const float* __restrict__ qinv,
                       const float* __restrict__ kinv, u16* __restrict__ regout){
    int wid = threadIdx.x>>6, lane = threadIdx.x&63;
    int pix = blockIdx.x*4 + wid;
    int h = pix>>8, w = pix&255;
    const u32* qp = (const u32*)(regin + (size_t)pix*REGC);
    u32 qu = qp[lane];
    float q0=blo(qu), q1=bhi(qu);
    float qn = qinv[pix];
    float res = 0.f;
    #pragma unroll
    for(int dy=-2;dy<=2;dy++){
        int hc = min(max(h+dy,0),255);
        #pragma unroll
        for(int dx=-2;dx<=2;dx++){
            int wc = min(max(w+dx,0),255);
            int npix = (hc<<8)+wc;
            const u32* kp = (const u32*)(regin + (size_t)npix*REGC + 128);
            u32 ku = kp[lane];
            float p = q0*blo(ku) + q1*bhi(ku);
            #pragma unroll
            for(int s=1;s<64;s<<=1) p += __shfl_xor(p,s);
            float cv = p*qn*kinv[npix];
            int o = (dy+2)*5 + (dx+2);
            if(lane==o) res = cv;
        }
    }
    if(lane<25) regout[(size_t)pix*REGC + 256 + lane] = f2b(res);
}

// ---------------- 10) weight rearrange: OIHW f32 -> MFMA B-fragment layout ---------
// w1f idx = (((tap*9 + kbg)*128 + co)*4 + g)*8 + j ; ci = kbg*32 + g*8 + j
// w2f idx = (((tap*4 + kbg)*64  + co)*4 + g)*8 + j ; ci = kbg*32 + g*8 + j
__global__ void k_wre(const float* __restrict__ w1, const float* __restrict__ w2,
                      u16* __restrict__ w1f, u16* __restrict__ w2f){
    int i = blockIdx.x*256 + threadIdx.x;
    if(i < 9*9*128*32){
        int j = i & 7;
        int gg = (i>>3)&3;
        int co = (i>>5)&127;
        int rest = i>>12;          // tap*9 + kbg
        int kbg = rest%9, tap = rest/9;
        int ci = kbg*32 + gg*8 + j;
        float v = (ci<282) ? w1[((size_t)co*282 + ci)*9 + tap] : 0.f;
        w1f[i] = f2b(v);
    }
    if(i < 9*4*64*32){
        int j = i & 7;
        int gg = (i>>3)&3;
        int co = (i>>5)&63;
        int rest = i>>11;          // tap*4 + kbg
        int kbg = rest&3, tap = rest>>2;
        int ci = kbg*32 + gg*8 + j;
        w2f[i] = f2b(w2[((size_t)co*128 + ci)*9 + tap]);
    }
}

// ---------------- 11+12) MFMA 3x3 conv (implicit GEMM over taps) -------------------
// 1-wave blocks, tile = 2 rows x 32 cols (64 px) x NCO couts.
// LDS: double-buffered 4 rows x 34 px x 64 ch bf16, XOR-swizzled 16B slots.
// Weights read as exact B-fragments (coalesced 16B/lane) from L2.

__device__ __forceinline__ void lda4(const uint4* sbuf, int ky, int kx, int kb,
                                     int lane15, int lgrp, bf16x8* ar){
    #pragma unroll
    for(int mf=0;mf<4;mf++){
        int spx  = (mf&1)*16 + lane15 + kx;       // 0..33
        int srow = (mf>>1) + ky;                  // 0..3
        int slot = (srow*34 + spx)*8 + ((kb*4 + lgrp) ^ (spx&7));
        ar[mf] = *(const bf16x8*)&sbuf[slot];
    }
}

template<int NF, int KBGT, int NCO>
__device__ __forceinline__ void ldbN(const u16* __restrict__ wf, int kbg, int tap,
                                     int lane15, int lgrp, bf16x8* br){
    #pragma unroll
    for(int nf=0;nf<NF;nf++){
        size_t idx = ((size_t)((tap*KBGT + kbg)*NCO + nf*16 + lane15))*4 + lgrp;
        br[nf] = *(const bf16x8*)(wf + idx*8);
    }
}

template<int NF, int KBGT, int NCO, int KBI>
__device__ __forceinline__ void conv_steps(const uint4* sbuf, const u16* __restrict__ wf,
                                           int kbgbase, int lane15, int lgrp,
                                           f32x4 (&acc)[4][NF]){
    bf16x8 a[2][4];
    bf16x8 b[2][NF];
    lda4(sbuf, 0,0,0, lane15, lgrp, a[0]);
    ldbN<NF,KBGT,NCO>(wf, kbgbase, 0, lane15, lgrp, b[0]);
    constexpr int NST = 9*KBI;
    #pragma unroll
    for(int s=0;s<NST;s++){
        int nx = s+1;
        if(nx < NST){
            int ky2,kx2,kb2;
            if(KBI==2){ ky2 = nx/6; kx2 = (nx>>1)%3; kb2 = nx&1; }
            else      { ky2 = nx/3; kx2 = nx%3;      kb2 = 0;   }
            lda4(sbuf, ky2,kx2,kb2, lane15, lgrp, a[nx&1]);
            ldbN<NF,KBGT,NCO>(wf, kbgbase+kb2, ky2*3+kx2, lane15, lgrp, b[nx&1]);
        }
        #pragma unroll
        for(int mf=0;mf<4;mf++)
            #pragma unroll
            for(int nf=0;nf<NF;nf++)
                acc[mf][nf] = mfma16(a[s&1][mf], b[s&1][nf], acc[mf][nf]);
    }
}

template<int CSTRIDE, int CINTOT, int NCO, int KBGT>
__global__ __launch_bounds__(64,1) void k_conv3(const u16* __restrict__ in,
                                                const u16* __restrict__ wf,
                                                const float* __restrict__ bias,
                                                u16* __restrict__ out){
    constexpr int NF = NCO/16;
    constexpr int NCHUNK = (CINTOT + 63)/64;
    __shared__ uint4 sT[2*1088];
    int t = threadIdx.x;
    int lane15 = t & 15, lgrp = t >> 4;
    int bid = blockIdx.x;
    int tx = bid & 7, ty = bid >> 3;
    int row0 = ty*2, col0 = tx*32;

    f32x4 acc[4][NF];
    #pragma unroll
    for(int nf=0;nf<NF;nf++){
        float bsv = bias[nf*16 + lane15];
        #pragma unroll
        for(int mf=0;mf<4;mf++) acc[mf][nf] = f32x4{bsv,bsv,bsv,bsv};
    }

    uint4 g[17];
    auto issue_loads = [&](int kc){
        #pragma unroll
        for(int it=0; it<17; ++it){
            int i = t + it*64;
            int srow = i/272, rem = i - srow*272;
            int spx = rem>>3, gg = rem&7;
            int gy = row0 - 1 + srow, gx = col0 - 1 + spx;
            int ch = kc + gg*8;
            bool ok = ((unsigned)gy<256u) && ((unsigned)gx<256u) && (ch+8 <= CINTOT);
            uint4 z = {0,0,0,0};
            const uint4* src = (const uint4*)(in + (size_t)(gy*256+gx)*CSTRIDE + ch);
            g[it] = ok ? *src : z;
        }
    };
    auto write_lds = [&](int cur){
        #pragma unroll
        for(int it=0; it<17; ++it){
            int i = t + it*64;
            int srow = i/272, rem = i - srow*272;
            int spx = rem>>3, gg = rem&7;
            sT[cur*1088 + (srow*34+spx)*8 + (gg ^ (spx&7))] = g[it];
        }
    };

    // prologue: stage chunk 0
    issue_loads(0);
    write_lds(0);
    int cur = 0;

    for(int j=0;j<NCHUNK;j++){
        if(j+1 < NCHUNK) issue_loads((j+1)*64);   // overlap HBM latency with MFMA block
        if(CINTOT==288 && j==NCHUNK-1)
            conv_steps<NF,KBGT,NCO,1>(&sT[cur*1088], wf, j*2, lane15, lgrp, acc);
        else
            conv_steps<NF,KBGT,NCO,2>(&sT[cur*1088], wf, j*2, lane15, lgrp, acc);
        if(j+1 < NCHUNK){
            write_lds(cur^1);
            cur ^= 1;
        }
    }

    // epilogue: leaky_relu + bf16 store. D frag: col(lane&15)=co, row=(lane>>4)*4+r = px
    #pragma unroll
    for(int mf=0;mf<4;mf++){
        int prow  = row0 + (mf>>1);
        int pcolb = col0 + (mf&1)*16 + lgrp*4;
        #pragma unroll
        for(int nf=0;nf<NF;nf++){
            int co = nf*16 + lane15;
            #pragma unroll
            for(int r=0;r<4;r++){
                int pix = (prow<<8) + pcolb + r;
                float v = acc[mf][nf][r];
                v = (v>0.f) ? v : 0.2f*v;
                out[(size_t)pix*NCO + co] = f2b(v);
            }
        }
    }
}

// ---------------- 13) flow (1x1 conv + tanh) + bilinear warp -----------------------
__device__ __forceinline__ float reflectc(float coord, float size){
    float c = fabsf(coord + 0.5f);
    float extra = fmodf(c, size);
    float flips = floorf(c/size);
    float fo = fmodf(flips, 2.0f);
    float r = (fo == 0.0f) ? (extra - 0.5f) : (size - extra - 0.5f);
    return fminf(fmaxf(r, 0.0f), size - 1.0f);
}

__global__ void k_flowwarp(const u16* __restrict__ h2, const float* __restrict__ w3,
                           const float* __restrict__ b3, const float* __restrict__ diff,
                           const float* __restrict__ x31, float* __restrict__ out){
    __shared__ float sw[130];
    for(int i=threadIdx.x;i<128;i+=256) sw[i]=w3[i];
    if(threadIdx.x<2) sw[128+threadIdx.x]=b3[threadIdx.x];
    __syncthreads();
    int pix = blockIdx.x*256 + threadIdx.x;
    if(pix>=HW) return;
    int h = pix>>8, w = pix&255;
    const uint4* h4 = (const uint4*)(h2 + (size_t)pix*64);
    float f0 = sw[128], f1 = sw[129];
    #pragma unroll
    for(int cc=0;cc<8;cc++){
        uint4 u = h4[cc];
        float vv[8] = {blo(u.x),bhi(u.x),blo(u.y),bhi(u.y),blo(u.z),bhi(u.z),blo(u.w),bhi(u.w)};
        #pragma unroll
        for(int j=0;j<8;j++){ int c = cc*8+j; f0 += sw[c]*vv[j]; f1 += sw[64+c]*vv[j]; }
    }
    float d = diff[pix];
    f0 = tanhf(f0)*2.0f*d;
    f1 = tanhf(f1)*2.0f*d;
    float ix = reflectc((float)w + f0, 256.f);
    float iy = reflectc((float)h + f1, 256.f);
    float x0 = floorf(ix), y0 = floorf(iy);
    float wx = ix-x0, wy = iy-y0;
    int x0i = min(max((int)x0,0),255);
    int x1i = min(x0i+1,255);
    int y0i = min(max((int)y0,0),255);
    int y1i = min(y0i+1,255);
    const float* p00 = x31 + ((size_t)((y0i<<8)+x0i))*32;
    const float* p01 = x31 + ((size_t)((y0i<<8)+x1i))*32;
    const float* p10 = x31 + ((size_t)((y1i<<8)+x0i))*32;
    const float* p11 = x31 + ((size_t)((y1i<<8)+x1i))*32;
    float w00=(1.f-wy)*(1.f-wx), w01=(1.f-wy)*wx, w10=wy*(1.f-wx), w11=wy*wx;
    float* ob = out + pix;
    #pragma unroll
    for(int c=0;c<CH;c++){
        ob[(size_t)c*HW] = w00*p00[c] + w01*p01[c] + w10*p10[c] + w11*p11[c];
    }
}

extern "C" void kernel_launch(void* const* d_in, const int* in_sizes, int n_in,
                              void* d_out, int out_size, void* d_ws, size_t ws_size,
                              hipStream_t stream) {
    const float* x    = (const float*)d_in[0];
    const float* y    = (const float*)d_in[1];
    const float* srf  = (const float*)d_in[2];
    const float* chw  = (const float*)d_in[3];
    const float* chb  = (const float*)d_in[4];
    const float* qw   = (const float*)d_in[5];
    const float* qb   = (const float*)d_in[6];
    const float* kw   = (const float*)d_in[7];
    const float* kb   = (const float*)d_in[8];
    const float* w1   = (const float*)d_in[9];
    const float* b1p  = (const float*)d_in[10];
    const float* w2   = (const float*)d_in[11];
    const float* b2p  = (const float*)d_in[12];
    const float* w3   = (const float*)d_in[13];
    const float* b3p  = (const float*)d_in[14];

    // Per-batch workspace (reused across b=0..3): ~78 MB total.
    char* ws = (char*)d_ws;
    size_t o = 0;
    float* x31   = (float*)(ws+o); o += (size_t)HW*32*4;       //  8.4 MB
    float* xp    = (float*)(ws+o); o += (size_t)3*HW*4;        //  0.8 MB
    float* xa    = (float*)(ws+o); o += (size_t)3*HW*4;        //  0.8 MB
    float* stats = (float*)(ws+o); o += 256;
    float* tmp   = (float*)(ws+o); o += (size_t)15*HW*4;       //  3.9 MB
    float* diff  = (float*)(ws+o); o += (size_t)HW*4;          //  0.3 MB
    float* qinv  = (float*)(ws+o); o += (size_t)HW*4;
    float* kinv  = (float*)(ws+o); o += (size_t)HW*4;
    u16* regin   = (u16*)(ws+o);   o += (size_t)HW*REGC*2;     // 37.7 MB
    u16* h1      = (u16*)(ws+o);   o += (size_t)HW*128*2;      // 16.8 MB
    u16* h2      = (u16*)(ws+o);   o += (size_t)HW*64*2;       //  8.4 MB
    u16* w1f     = (u16*)(ws+o);   o += (size_t)9*9*128*32*2;  //  0.66 MB
    u16* w2f     = (u16*)(ws+o);   o += (size_t)9*4*64*32*2;   //  0.15 MB

    k_wre<<<1296, 256, 0, stream>>>(w1, w2, w1f, w2f);

    for(int b=0;b<4;b++){
        const float* xb  = x + (size_t)b*CIN2*HW;
        const float* yb  = y + (size_t)b*CM*HW;
        float* outb      = (float*)d_out + (size_t)b*CH*HW;

        k_conv_half<<<256,  256, 0, stream>>>(xb, chw, chb, x31);
        k_project  <<<256,  256, 0, stream>>>(x31, srf, xp);
        k_stats    <<<6,    256, 0, stream>>>(xp, yb, stats);
        k_align    <<<768,  256, 0, stream>>>(xp, stats, xa);
        k_ssim_h   <<<768,  256, 0, stream>>>(xa, yb, tmp);
        k_ssim_v   <<<256,  256, 0, stream>>>(tmp, diff, regin);
        k_qk       <<<16384,128, 0, stream>>>(x31, yb, qw, qb, kw, kb, regin);
        k_norms    <<<16384,256, 0, stream>>>(regin, qinv, kinv);
        k_corr     <<<16384,256, 0, stream>>>(regin, qinv, kinv, regin);
        k_conv3<288,288,128,9><<<1024, 64, 0, stream>>>(regin, w1f, b1p, h1);
        k_conv3<128,128, 64,4><<<1024, 64, 0, stream>>>(h1, w2f, b2p, h2);
        k_flowwarp <<<256,  256, 0, stream>>>(h2, w3, b3p, diff, x31, outb);
    }
}

// Round 4
// 1535.100 us; speedup vs baseline: 4.1893x; 1.1427x over previous
//
#include <hip/hip_runtime.h>
#include <hip/hip_bf16.h>
#include <math.h>

// Per-batch pipeline; r1/r2 are MFMA implicit-GEMM convs.
// R4: k_corr -> lane-pair-per-pixel (was wave-per-pixel); k_norms fused into k_qk.

#define HH 256
#define WWI 256
#define HW 65536
#define CH 31
#define CIN2 62
#define CM 3
#define CE 128
#define REGC 288
#define C1S 1e-4f
#define C2S 9e-4f

typedef unsigned short u16;
typedef unsigned int u32;
typedef short bf16x8 __attribute__((ext_vector_type(8)));   // 8 bf16 in 4 VGPRs
typedef float f32x4 __attribute__((ext_vector_type(4)));

__device__ __forceinline__ float blo(u32 u){ return __uint_as_float(u << 16); }
__device__ __forceinline__ float bhi(u32 u){ return __uint_as_float(u & 0xffff0000u); }
__device__ __forceinline__ float b1f(u16 u){ return __uint_as_float(((u32)u) << 16); }
__device__ __forceinline__ u16 f2b(float f){
    u32 u = __float_as_uint(f);
    u32 r = (u + 0x7fffu + ((u >> 16) & 1u)) >> 16;
    return (u16)r;
}
__device__ __forceinline__ f32x4 mfma16(bf16x8 a, bf16x8 b, f32x4 c){
    return __builtin_amdgcn_mfma_f32_16x16x32_bf16(a, b, c, 0, 0, 0);
}

// ---------------- 1) conv_half (one batch): (62,H,W) f32 -> x31 NHWC f32 [pix][32]
__global__ void k_conv_half(const float* __restrict__ x, const float* __restrict__ w,
                            const float* __restrict__ bias, float* __restrict__ x31){
    __shared__ float sw[CH*CIN2];
    __shared__ float sb[CH+1];
    for(int i=threadIdx.x;i<CH*CIN2;i+=256) sw[i]=w[i];
    for(int i=threadIdx.x;i<CH;i+=256) sb[i]=bias[i];
    __syncthreads();
    int pix = blockIdx.x*256 + threadIdx.x;
    if(pix>=HW) return;
    float acc[CH];
    #pragma unroll
    for(int c=0;c<CH;c++) acc[c]=sb[c];
    for(int ci=0;ci<CIN2;ci++){
        float xv = x[(size_t)ci*HW + pix];
        #pragma unroll
        for(int c=0;c<CH;c++) acc[c] += sw[c*CIN2+ci]*xv;
    }
    float* o = x31 + (size_t)pix*32;
    #pragma unroll
    for(int c=0;c<CH;c++) o[c]=acc[c];
    o[31]=0.f;
}

// ---------------- 2) project: xp = clip(SRF @ x31, -1, 1), layout [3][HW] --------
__global__ void k_project(const float* __restrict__ x31, const float* __restrict__ srf,
                          float* __restrict__ xp){
    __shared__ float s[CM*CH];
    for(int i=threadIdx.x;i<CM*CH;i+=256) s[i]=srf[i];
    __syncthreads();
    int pix = blockIdx.x*256 + threadIdx.x;
    if(pix>=HW) return;
    const float* xr = x31 + (size_t)pix*32;
    #pragma unroll
    for(int m=0;m<CM;m++){
        float acc=0.f;
        #pragma unroll
        for(int c=0;c<CH;c++) acc += s[m*CH+c]*xr[c];
        acc = fminf(fmaxf(acc,-1.f),1.f);
        xp[(size_t)m*HW + pix] = acc;
    }
}

// ---------------- 3) stats: mean/std(ddof=1); planes 0..2 = xp, 3..5 = y ---------
__global__ void k_stats(const float* __restrict__ xp, const float* __restrict__ y,
                        float* __restrict__ stats){
    int p = blockIdx.x;
    const float* src = (p<3) ? (xp + (size_t)p*HW) : (y + (size_t)(p-3)*HW);
    float s=0.f, ss=0.f;
    for(int i=threadIdx.x;i<HW;i+=256){ float v=src[i]; s+=v; ss+=v*v; }
    __shared__ float rs[256], rss[256];
    rs[threadIdx.x]=s; rss[threadIdx.x]=ss;
    __syncthreads();
    for(int st=128;st>0;st>>=1){
        if(threadIdx.x<st){ rs[threadIdx.x]+=rs[threadIdx.x+st]; rss[threadIdx.x]+=rss[threadIdx.x+st]; }
        __syncthreads();
    }
    if(threadIdx.x==0){
        float mean = rs[0]/(float)HW;
        float var = (rss[0] - rs[0]*rs[0]/(float)HW) / (float)(HW-1);
        stats[p*2] = mean;
        stats[p*2+1] = sqrtf(fmaxf(var,0.f));
    }
}

// ---------------- 4) align ---------------------------------------------------------
__global__ void k_align(const float* __restrict__ xp, const float* __restrict__ stats,
                        float* __restrict__ xa){
    int i = blockIdx.x*256 + threadIdx.x;
    if(i>=3*HW) return;
    int plane = i>>16;
    float sm = stats[plane*2], ssd = stats[plane*2+1];
    float rm = stats[(plane+3)*2], rsd = stats[(plane+3)*2+1];
    float v = (xp[i]-sm)/(ssd+1e-6f)*rsd + rm;
    xa[i] = fminf(fmaxf(v,-1.f),1.f);
}

// ---------------- 5) ssim horizontal gaussian pass ---------------------------------
__global__ void k_ssim_h(const float* __restrict__ xa, const float* __restrict__ y,
                         float* __restrict__ tmp){
    int i = blockIdx.x*256 + threadIdx.x;
    if(i>=3*HW) return;
    int plane = i>>16, hw = i&65535, h = hw>>8, w = hw&255;
    float g[9]; float gs=0.f;
    #pragma unroll
    for(int t=0;t<9;t++){ float cc=(float)(t-4); g[t]=expf(-cc*cc/4.5f); gs+=g[t]; }
    float inv = 1.f/gs;
    float s0=0,s1=0,s2=0,s3=0,s4=0;
    const float* xr = xa + (size_t)plane*HW + (size_t)h*256;
    const float* yr = y  + (size_t)plane*HW + (size_t)h*256;
    #pragma unroll
    for(int t=0;t<9;t++){
        int wc = w + t - 4;
        if(wc>=0 && wc<256){
            float gg = g[t]*inv;
            float a = xr[wc], b = yr[wc];
            s0+=gg*a; s1+=gg*b; s2+=gg*a*a; s3+=gg*b*b; s4+=gg*a*b;
        }
    }
    size_t base = (size_t)plane*5*HW + hw;
    tmp[base]=s0; tmp[base+HW]=s1; tmp[base+2*(size_t)HW]=s2; tmp[base+3*(size_t)HW]=s3; tmp[base+4*(size_t)HW]=s4;
}

// ---------------- 6) ssim vertical pass + difficulty -> diff, regin ch281 ---------
__global__ void k_ssim_v(const float* __restrict__ tmp, float* __restrict__ diff,
                         u16* __restrict__ regin){
    int pix = blockIdx.x*256 + threadIdx.x;
    if(pix>=HW) return;
    int h = pix>>8, w = pix&255;
    float g[9]; float gs=0.f;
    #pragma unroll
    for(int t=0;t<9;t++){ float cc=(float)(t-4); g[t]=expf(-cc*cc/4.5f); gs+=g[t]; }
    float inv = 1.f/gs;
    float msum = 0.f;
    for(int m=0;m<3;m++){
        float v0=0,v1=0,v2=0,v3=0,v4=0;
        #pragma unroll
        for(int t=0;t<9;t++){
            int hc = h + t - 4;
            if(hc>=0 && hc<256){
                float gg = g[t]*inv;
                size_t base = (size_t)m*5*HW + (size_t)hc*256 + w;
                v0+=gg*tmp[base]; v1+=gg*tmp[base+HW]; v2+=gg*tmp[base+2*(size_t)HW];
                v3+=gg*tmp[base+3*(size_t)HW]; v4+=gg*tmp[base+4*(size_t)HW];
            }
        }
        float mu1=v0, mu2=v1;
        float mu1s=mu1*mu1, mu2s=mu2*mu2, mu12=mu1*mu2;
        float sg1=v2-mu1s, sg2=v3-mu2s, sg12=v4-mu12;
        float num=(2.f*mu12+C1S)*(2.f*sg12+C2S);
        float den=(mu1s+mu2s+C1S)*(sg1+sg2+C2S);
        msum += num/den;
    }
    float ss = msum*(1.f/3.f);
    float d = fminf(fmaxf((1.f-ss)*0.5f,0.f),1.f);
    diff[pix] = d;
    regin[(size_t)pix*REGC + 281] = f2b(d);
}

// ---------------- 7) q,k 1x1 convs -> regin bf16, + fused l2-norm reduce ----------
__global__ void k_qk(const float* __restrict__ x31, const float* __restrict__ y,
                     const float* __restrict__ qw, const float* __restrict__ qb,
                     const float* __restrict__ kw, const float* __restrict__ kb,
                     u16* __restrict__ regin, float* __restrict__ qinv,
                     float* __restrict__ kinv){
    __shared__ float sqw[CE*CH];
    __shared__ float skw[CE*CM];
    __shared__ float sqb[CE], skb[CE];
    __shared__ float redq[4][2], redk[4][2];
    for(int i=threadIdx.x;i<CE*CH;i+=128) sqw[i]=qw[i];
    for(int i=threadIdx.x;i<CE*CM;i+=128) skw[i]=kw[i];
    if(threadIdx.x<CE){ sqb[threadIdx.x]=qb[threadIdx.x]; skb[threadIdx.x]=kb[threadIdx.x]; }
    __syncthreads();
    int co = threadIdx.x, wid = co>>6, lane = co&63;
    int p0 = blockIdx.x*4;
    for(int pp=0;pp<4;pp++){
        int pix = p0+pp;
        const float* xr = x31 + (size_t)pix*32;
        float acc = sqb[co];
        #pragma unroll
        for(int c=0;c<CH;c++) acc += sqw[co*CH+c]*xr[c];
        regin[(size_t)pix*REGC + co] = f2b(acc);
        float ack = skb[co];
        #pragma unroll
        for(int c=0;c<CM;c++) ack += skw[co*CM+c]*y[(size_t)c*HW + pix];
        regin[(size_t)pix*REGC + 128 + co] = f2b(ack);
        if(co<6) regin[(size_t)pix*REGC + 282 + co] = 0;  // zero channel pad
        // fused l2 norms (reduce over all 128 couts = 2 waves)
        float sq = acc*acc, sk2 = ack*ack;
        #pragma unroll
        for(int t=1;t<64;t<<=1){ sq += __shfl_xor(sq,t); sk2 += __shfl_xor(sk2,t); }
        if(lane==0){ redq[pp][wid]=sq; redk[pp][wid]=sk2; }
        __syncthreads();
        if(threadIdx.x==0)  qinv[pix] = 1.f/fmaxf(sqrtf(redq[pp][0]+redq[pp][1]),1e-12f);
        if(threadIdx.x==64) kinv[pix] = 1.f/fmaxf(sqrtf(redk[pp][0]+redk[pp][1]),1e-12f);
    }
}

// ---------------- 9) correlation volume: lane-pair per pixel ----------------------
// Each pixel handled by 2 adjacent lanes (64 ch each). q in registers; k read
// direct from global (L1/L2-resident, 25x spatial reuse). One shfl_xor(1) per
// offset merges the halves.
__global__ __launch_bounds__(256) void k_corr(const u16* __restrict__ regin,
                                              const float* __restrict__ qinv,
                                              const float* __restrict__ kinv,
                                              u16* __restrict__ regout){
    int t = threadIdx.x;
    int half = t & 1, pidx = t >> 1;           // 128 pixels per block
    int bid = blockIdx.x;
    int tx = bid & 7, ty = bid >> 3;            // 8 x 64 grid
    int w = tx*32 + (pidx & 31);
    int h = ty*4 + (pidx >> 5);
    int pix = (h<<8) + w;

    uint4 q[8];
    const uint4* qp = (const uint4*)(regin + (size_t)pix*REGC) + half*8;
    #pragma unroll
    for(int i=0;i<8;i++) q[i] = qp[i];
    float qn = qinv[pix];

    #pragma unroll
    for(int dy=-2;dy<=2;dy++){
        int hc = min(max(h+dy,0),255);
        #pragma unroll
        for(int dx=-2;dx<=2;dx++){
            int wc = min(max(w+dx,0),255);
            int npix = (hc<<8)+wc;
            const uint4* kp = (const uint4*)(regin + (size_t)npix*REGC + 128) + half*8;
            float s = 0.f;
            #pragma unroll
            for(int i=0;i<8;i++){
                uint4 kv = kp[i];
                uint4 qv = q[i];
                s += blo(qv.x)*blo(kv.x) + bhi(qv.x)*bhi(kv.x);
                s += blo(qv.y)*blo(kv.y) + bhi(qv.y)*bhi(kv.y);
                s += blo(qv.z)*blo(kv.z) + bhi(qv.z)*bhi(kv.z);
                s += blo(qv.w)*blo(kv.w) + bhi(qv.w)*bhi(kv.w);
            }
            s += __shfl_xor(s, 1);              // merge channel halves
            int o = (dy+2)*5 + (dx+2);
            bool mine = half ? (o>=13) : (o<13);
            if(mine) regout[(size_t)pix*REGC + 256 + o] = f2b(s*qn*kinv[npix]);
        }
    }
}

// ---------------- 10) weight rearrange: OIHW f32 -> MFMA B-fragment layout ---------
__global__ void k_wre(const float* __restrict__ w1, const float* __restrict__ w2,
                      u16* __restrict__ w1f, u16* __restrict__ w2f){
    int i = blockIdx.x*256 + threadIdx.x;
    if(i < 9*9*128*32){
        int j = i & 7;
        int gg = (i>>3)&3;
        int co = (i>>5)&127;
        int rest = i>>12;          // tap*9 + kbg
        int kbg = rest%9, tap = rest/9;
        int ci = kbg*32 + gg*8 + j;
        float v = (ci<282) ? w1[((size_t)co*282 + ci)*9 + tap] : 0.f;
        w1f[i] = f2b(v);
    }
    if(i < 9*4*64*32){
        int j = i & 7;
        int gg = (i>>3)&3;
        int co = (i>>5)&63;
        int rest = i>>11;          // tap*4 + kbg
        int kbg = rest&3, tap = rest>>2;
        int ci = kbg*32 + gg*8 + j;
        w2f[i] = f2b(w2[((size_t)co*128 + ci)*9 + tap]);
    }
}

// ---------------- 11+12) MFMA 3x3 conv (implicit GEMM over taps) -------------------
__device__ __forceinline__ void lda4(const uint4* sbuf, int ky, int kx, int kb,
                                     int lane15, int lgrp, bf16x8* ar){
    #pragma unroll
    for(int mf=0;mf<4;mf++){
        int spx  = (mf&1)*16 + lane15 + kx;       // 0..33
        int srow = (mf>>1) + ky;                  // 0..3
        int slot = (srow*34 + spx)*8 + ((kb*4 + lgrp) ^ (spx&7));
        ar[mf] = *(const bf16x8*)&sbuf[slot];
    }
}

template<int NF, int KBGT, int NCO>
__device__ __forceinline__ void ldbN(const u16* __restrict__ wf, int kbg, int tap,
                                     int lane15, int lgrp, bf16x8* br){
    #pragma unroll
    for(int nf=0;nf<NF;nf++){
        size_t idx = ((size_t)((tap*KBGT + kbg)*NCO + nf*16 + lane15))*4 + lgrp;
        br[nf] = *(const bf16x8*)(wf + idx*8);
    }
}

template<int NF, int KBGT, int NCO, int KBI>
__device__ __forceinline__ void conv_steps(const uint4* sbuf, const u16* __restrict__ wf,
                                           int kbgbase, int lane15, int lgrp,
                                           f32x4 (&acc)[4][NF]){
    bf16x8 a[2][4];
    bf16x8 b[2][NF];
    lda4(sbuf, 0,0,0, lane15, lgrp, a[0]);
    ldbN<NF,KBGT,NCO>(wf, kbgbase, 0, lane15, lgrp, b[0]);
    constexpr int NST = 9*KBI;
    #pragma unroll
    for(int s=0;s<NST;s++){
        int nx = s+1;
        if(nx < NST){
            int ky2,kx2,kb2;
            if(KBI==2){ ky2 = nx/6; kx2 = (nx>>1)%3; kb2 = nx&1; }
            else      { ky2 = nx/3; kx2 = nx%3;      kb2 = 0;   }
            lda4(sbuf, ky2,kx2,kb2, lane15, lgrp, a[nx&1]);
            ldbN<NF,KBGT,NCO>(wf, kbgbase+kb2, ky2*3+kx2, lane15, lgrp, b[nx&1]);
        }
        #pragma unroll
        for(int mf=0;mf<4;mf++)
            #pragma unroll
            for(int nf=0;nf<NF;nf++)
                acc[mf][nf] = mfma16(a[s&1][mf], b[s&1][nf], acc[mf][nf]);
    }
}

template<int CSTRIDE, int CINTOT, int NCO, int KBGT>
__global__ __launch_bounds__(64,1) void k_conv3(const u16* __restrict__ in,
                                                const u16* __restrict__ wf,
                                                const float* __restrict__ bias,
                                                u16* __restrict__ out){
    constexpr int NF = NCO/16;
    constexpr int NCHUNK = (CINTOT + 63)/64;
    __shared__ uint4 sT[2*1088];
    int t = threadIdx.x;
    int lane15 = t & 15, lgrp = t >> 4;
    int bid = blockIdx.x;
    int tx = bid & 7, ty = bid >> 3;
    int row0 = ty*2, col0 = tx*32;

    f32x4 acc[4][NF];
    #pragma unroll
    for(int nf=0;nf<NF;nf++){
        float bsv = bias[nf*16 + lane15];
        #pragma unroll
        for(int mf=0;mf<4;mf++) acc[mf][nf] = f32x4{bsv,bsv,bsv,bsv};
    }

    uint4 g[17];
    auto issue_loads = [&](int kc){
        #pragma unroll
        for(int it=0; it<17; ++it){
            int i = t + it*64;
            int srow = i/272, rem = i - srow*272;
            int spx = rem>>3, gg = rem&7;
            int gy = row0 - 1 + srow, gx = col0 - 1 + spx;
            int ch = kc + gg*8;
            bool ok = ((unsigned)gy<256u) && ((unsigned)gx<256u) && (ch+8 <= CINTOT);
            uint4 z = {0,0,0,0};
            const uint4* src = (const uint4*)(in + (size_t)(gy*256+gx)*CSTRIDE + ch);
            g[it] = ok ? *src : z;
        }
    };
    auto write_lds = [&](int cur){
        #pragma unroll
        for(int it=0; it<17; ++it){
            int i = t + it*64;
            int srow = i/272, rem = i - srow*272;
            int spx = rem>>3, gg = rem&7;
            sT[cur*1088 + (srow*34+spx)*8 + (gg ^ (spx&7))] = g[it];
        }
    };

    issue_loads(0);
    write_lds(0);
    int cur = 0;

    for(int j=0;j<NCHUNK;j++){
        if(j+1 < NCHUNK) issue_loads((j+1)*64);
        if(CINTOT==288 && j==NCHUNK-1)
            conv_steps<NF,KBGT,NCO,1>(&sT[cur*1088], wf, j*2, lane15, lgrp, acc);
        else
            conv_steps<NF,KBGT,NCO,2>(&sT[cur*1088], wf, j*2, lane15, lgrp, acc);
        if(j+1 < NCHUNK){
            write_lds(cur^1);
            cur ^= 1;
        }
    }

    #pragma unroll
    for(int mf=0;mf<4;mf++){
        int prow  = row0 + (mf>>1);
        int pcolb = col0 + (mf&1)*16 + lgrp*4;
        #pragma unroll
        for(int nf=0;nf<NF;nf++){
            int co = nf*16 + lane15;
            #pragma unroll
            for(int r=0;r<4;r++){
                int pix = (prow<<8) + pcolb + r;
                float v = acc[mf][nf][r];
                v = (v>0.f) ? v : 0.2f*v;
                out[(size_t)pix*NCO + co] = f2b(v);
            }
        }
    }
}

// ---------------- 13) flow (1x1 conv + tanh) + bilinear warp -----------------------
__device__ __forceinline__ float reflectc(float coord, float size){
    float c = fabsf(coord + 0.5f);
    float extra = fmodf(c, size);
    float flips = floorf(c/size);
    float fo = fmodf(flips, 2.0f);
    float r = (fo == 0.0f) ? (extra - 0.5f) : (size - extra - 0.5f);
    return fminf(fmaxf(r, 0.0f), size - 1.0f);
}

__global__ void k_flowwarp(const u16* __restrict__ h2, const float* __restrict__ w3,
                           const float* __restrict__ b3, const float* __restrict__ diff,
                           const float* __restrict__ x31, float* __restrict__ out){
    __shared__ float sw[130];
    for(int i=threadIdx.x;i<128;i+=256) sw[i]=w3[i];
    if(threadIdx.x<2) sw[128+threadIdx.x]=b3[threadIdx.x];
    __syncthreads();
    int pix = blockIdx.x*256 + threadIdx.x;
    if(pix>=HW) return;
    int h = pix>>8, w = pix&255;
    const uint4* h4 = (const uint4*)(h2 + (size_t)pix*64);
    float f0 = sw[128], f1 = sw[129];
    #pragma unroll
    for(int cc=0;cc<8;cc++){
        uint4 u = h4[cc];
        float vv[8] = {blo(u.x),bhi(u.x),blo(u.y),bhi(u.y),blo(u.z),bhi(u.z),blo(u.w),bhi(u.w)};
        #pragma unroll
        for(int j=0;j<8;j++){ int c = cc*8+j; f0 += sw[c]*vv[j]; f1 += sw[64+c]*vv[j]; }
    }
    float d = diff[pix];
    f0 = tanhf(f0)*2.0f*d;
    f1 = tanhf(f1)*2.0f*d;
    float ix = reflectc((float)w + f0, 256.f);
    float iy = reflectc((float)h + f1, 256.f);
    float x0 = floorf(ix), y0 = floorf(iy);
    float wx = ix-x0, wy = iy-y0;
    int x0i = min(max((int)x0,0),255);
    int x1i = min(x0i+1,255);
    int y0i = min(max((int)y0,0),255);
    int y1i = min(y0i+1,255);
    const float* p00 = x31 + ((size_t)((y0i<<8)+x0i))*32;
    const float* p01 = x31 + ((size_t)((y0i<<8)+x1i))*32;
    const float* p10 = x31 + ((size_t)((y1i<<8)+x0i))*32;
    const float* p11 = x31 + ((size_t)((y1i<<8)+x1i))*32;
    float w00=(1.f-wy)*(1.f-wx), w01=(1.f-wy)*wx, w10=wy*(1.f-wx), w11=wy*wx;
    float* ob = out + pix;
    #pragma unroll
    for(int c=0;c<CH;c++){
        ob[(size_t)c*HW] = w00*p00[c] + w01*p01[c] + w10*p10[c] + w11*p11[c];
    }
}

extern "C" void kernel_launch(void* const* d_in, const int* in_sizes, int n_in,
                              void* d_out, int out_size, void* d_ws, size_t ws_size,
                              hipStream_t stream) {
    const float* x    = (const float*)d_in[0];
    const float* y    = (const float*)d_in[1];
    const float* srf  = (const float*)d_in[2];
    const float* chw  = (const float*)d_in[3];
    const float* chb  = (const float*)d_in[4];
    const float* qw   = (const float*)d_in[5];
    const float* qb   = (const float*)d_in[6];
    const float* kw   = (const float*)d_in[7];
    const float* kb   = (const float*)d_in[8];
    const float* w1   = (const float*)d_in[9];
    const float* b1p  = (const float*)d_in[10];
    const float* w2   = (const float*)d_in[11];
    const float* b2p  = (const float*)d_in[12];
    const float* w3   = (const float*)d_in[13];
    const float* b3p  = (const float*)d_in[14];

    // Per-batch workspace (reused across b=0..3): ~78 MB total.
    char* ws = (char*)d_ws;
    size_t o = 0;
    float* x31   = (float*)(ws+o); o += (size_t)HW*32*4;       //  8.4 MB
    float* xp    = (float*)(ws+o); o += (size_t)3*HW*4;        //  0.8 MB
    float* xa    = (float*)(ws+o); o += (size_t)3*HW*4;        //  0.8 MB
    float* stats = (float*)(ws+o); o += 256;
    float* tmp   = (float*)(ws+o); o += (size_t)15*HW*4;       //  3.9 MB
    float* diff  = (float*)(ws+o); o += (size_t)HW*4;          //  0.3 MB
    float* qinv  = (float*)(ws+o); o += (size_t)HW*4;
    float* kinv  = (float*)(ws+o); o += (size_t)HW*4;
    u16* regin   = (u16*)(ws+o);   o += (size_t)HW*REGC*2;     // 37.7 MB
    u16* h1      = (u16*)(ws+o);   o += (size_t)HW*128*2;      // 16.8 MB
    u16* h2      = (u16*)(ws+o);   o += (size_t)HW*64*2;       //  8.4 MB
    u16* w1f     = (u16*)(ws+o);   o += (size_t)9*9*128*32*2;  //  0.66 MB
    u16* w2f     = (u16*)(ws+o);   o += (size_t)9*4*64*32*2;   //  0.15 MB

    k_wre<<<1296, 256, 0, stream>>>(w1, w2, w1f, w2f);

    for(int b=0;b<4;b++){
        const float* xb  = x + (size_t)b*CIN2*HW;
        const float* yb  = y + (size_t)b*CM*HW;
        float* outb      = (float*)d_out + (size_t)b*CH*HW;

        k_conv_half<<<256,  256, 0, stream>>>(xb, chw, chb, x31);
        k_project  <<<256,  256, 0, stream>>>(x31, srf, xp);
        k_stats    <<<6,    256, 0, stream>>>(xp, yb, stats);
        k_align    <<<768,  256, 0, stream>>>(xp, stats, xa);
        k_ssim_h   <<<768,  256, 0, stream>>>(xa, yb, tmp);
        k_ssim_v   <<<256,  256, 0, stream>>>(tmp, diff, regin);
        k_qk       <<<16384,128, 0, stream>>>(x31, yb, qw, qb, kw, kb, regin, qinv, kinv);
        k_corr     <<<512,  256, 0, stream>>>(regin, qinv, kinv, regin);
        k_conv3<288,288,128,9><<<1024, 64, 0, stream>>>(regin, w1f, b1p, h1);
        k_conv3<128,128, 64,4><<<1024, 64, 0, stream>>>(h1, w2f, b2p, h2);
        k_flowwarp <<<256,  256, 0, stream>>>(h2, w3, b3p, diff, x31, outb);
    }
}

// Round 6
// 1331.878 us; speedup vs baseline: 4.8285x; 1.1526x over previous
//
#include <hip/hip_runtime.h>
#include <hip/hip_bf16.h>
#include <math.h>

// Per-batch pipeline; r1/r2 are MFMA implicit-GEMM convs.
// R6: global_load_lds staging fixed -- ALL lanes issue the DMA (halo lanes read
// from a zeroed dummy buffer) so the wave-uniform LDS base (readfirstlane) is
// always lane 0's address. R5's per-lane exec-masking shifted edge-tile writes.

#define HH 256
#define WWI 256
#define HW 65536
#define CH 31
#define CIN2 62
#define CM 3
#define CE 128
#define REGC 288
#define C1S 1e-4f
#define C2S 9e-4f

typedef unsigned short u16;
typedef unsigned int u32;
typedef short bf16x8 __attribute__((ext_vector_type(8)));   // 8 bf16 in 4 VGPRs
typedef float f32x4 __attribute__((ext_vector_type(4)));

__device__ __forceinline__ float blo(u32 u){ return __uint_as_float(u << 16); }
__device__ __forceinline__ float bhi(u32 u){ return __uint_as_float(u & 0xffff0000u); }
__device__ __forceinline__ float b1f(u16 u){ return __uint_as_float(((u32)u) << 16); }
__device__ __forceinline__ u16 f2b(float f){
    u32 u = __float_as_uint(f);
    u32 r = (u + 0x7fffu + ((u >> 16) & 1u)) >> 16;
    return (u16)r;
}
__device__ __forceinline__ f32x4 mfma16(bf16x8 a, bf16x8 b, f32x4 c){
    return __builtin_amdgcn_mfma_f32_16x16x32_bf16(a, b, c, 0, 0, 0);
}

// ---------------- 1) conv_half (one batch): (62,H,W) f32 -> x31 NHWC f32 [pix][32]
__global__ void k_conv_half(const float* __restrict__ x, const float* __restrict__ w,
                            const float* __restrict__ bias, float* __restrict__ x31){
    __shared__ float sw[CH*CIN2];
    __shared__ float sb[CH+1];
    for(int i=threadIdx.x;i<CH*CIN2;i+=256) sw[i]=w[i];
    for(int i=threadIdx.x;i<CH;i+=256) sb[i]=bias[i];
    __syncthreads();
    int pix = blockIdx.x*256 + threadIdx.x;
    if(pix>=HW) return;
    float acc[CH];
    #pragma unroll
    for(int c=0;c<CH;c++) acc[c]=sb[c];
    for(int ci=0;ci<CIN2;ci++){
        float xv = x[(size_t)ci*HW + pix];
        #pragma unroll
        for(int c=0;c<CH;c++) acc[c] += sw[c*CIN2+ci]*xv;
    }
    float* o = x31 + (size_t)pix*32;
    #pragma unroll
    for(int c=0;c<CH;c++) o[c]=acc[c];
    o[31]=0.f;
}

// ---------------- 2) project: xp = clip(SRF @ x31, -1, 1), layout [3][HW] --------
__global__ void k_project(const float* __restrict__ x31, const float* __restrict__ srf,
                          float* __restrict__ xp){
    __shared__ float s[CM*CH];
    for(int i=threadIdx.x;i<CM*CH;i+=256) s[i]=srf[i];
    __syncthreads();
    int pix = blockIdx.x*256 + threadIdx.x;
    if(pix>=HW) return;
    const float* xr = x31 + (size_t)pix*32;
    #pragma unroll
    for(int m=0;m<CM;m++){
        float acc=0.f;
        #pragma unroll
        for(int c=0;c<CH;c++) acc += s[m*CH+c]*xr[c];
        acc = fminf(fmaxf(acc,-1.f),1.f);
        xp[(size_t)m*HW + pix] = acc;
    }
}

// ---------------- 3) stats: mean/std(ddof=1); planes 0..2 = xp, 3..5 = y ---------
__global__ void k_stats(const float* __restrict__ xp, const float* __restrict__ y,
                        float* __restrict__ stats){
    int p = blockIdx.x;
    const float* src = (p<3) ? (xp + (size_t)p*HW) : (y + (size_t)(p-3)*HW);
    float s=0.f, ss=0.f;
    for(int i=threadIdx.x;i<HW;i+=256){ float v=src[i]; s+=v; ss+=v*v; }
    __shared__ float rs[256], rss[256];
    rs[threadIdx.x]=s; rss[threadIdx.x]=ss;
    __syncthreads();
    for(int st=128;st>0;st>>=1){
        if(threadIdx.x<st){ rs[threadIdx.x]+=rs[threadIdx.x+st]; rss[threadIdx.x]+=rss[threadIdx.x+st]; }
        __syncthreads();
    }
    if(threadIdx.x==0){
        float mean = rs[0]/(float)HW;
        float var = (rss[0] - rs[0]*rs[0]/(float)HW) / (float)(HW-1);
        stats[p*2] = mean;
        stats[p*2+1] = sqrtf(fmaxf(var,0.f));
    }
}

// ---------------- 4) align ---------------------------------------------------------
__global__ void k_align(const float* __restrict__ xp, const float* __restrict__ stats,
                        float* __restrict__ xa){
    int i = blockIdx.x*256 + threadIdx.x;
    if(i>=3*HW) return;
    int plane = i>>16;
    float sm = stats[plane*2], ssd = stats[plane*2+1];
    float rm = stats[(plane+3)*2], rsd = stats[(plane+3)*2+1];
    float v = (xp[i]-sm)/(ssd+1e-6f)*rsd + rm;
    xa[i] = fminf(fmaxf(v,-1.f),1.f);
}

// ---------------- 5) ssim horizontal gaussian pass ---------------------------------
__global__ void k_ssim_h(const float* __restrict__ xa, const float* __restrict__ y,
                         float* __restrict__ tmp){
    int i = blockIdx.x*256 + threadIdx.x;
    if(i>=3*HW) return;
    int plane = i>>16, hw = i&65535, h = hw>>8, w = hw&255;
    float g[9]; float gs=0.f;
    #pragma unroll
    for(int t=0;t<9;t++){ float cc=(float)(t-4); g[t]=expf(-cc*cc/4.5f); gs+=g[t]; }
    float inv = 1.f/gs;
    float s0=0,s1=0,s2=0,s3=0,s4=0;
    const float* xr = xa + (size_t)plane*HW + (size_t)h*256;
    const float* yr = y  + (size_t)plane*HW + (size_t)h*256;
    #pragma unroll
    for(int t=0;t<9;t++){
        int wc = w + t - 4;
        if(wc>=0 && wc<256){
            float gg = g[t]*inv;
            float a = xr[wc], b = yr[wc];
            s0+=gg*a; s1+=gg*b; s2+=gg*a*a; s3+=gg*b*b; s4+=gg*a*b;
        }
    }
    size_t base = (size_t)plane*5*HW + hw;
    tmp[base]=s0; tmp[base+HW]=s1; tmp[base+2*(size_t)HW]=s2; tmp[base+3*(size_t)HW]=s3; tmp[base+4*(size_t)HW]=s4;
}

// ---------------- 6) ssim vertical pass + difficulty -> diff, regin ch281 ---------
__global__ void k_ssim_v(const float* __restrict__ tmp, float* __restrict__ diff,
                         u16* __restrict__ regin){
    int pix = blockIdx.x*256 + threadIdx.x;
    if(pix>=HW) return;
    int h = pix>>8, w = pix&255;
    float g[9]; float gs=0.f;
    #pragma unroll
    for(int t=0;t<9;t++){ float cc=(float)(t-4); g[t]=expf(-cc*cc/4.5f); gs+=g[t]; }
    float inv = 1.f/gs;
    float msum = 0.f;
    for(int m=0;m<3;m++){
        float v0=0,v1=0,v2=0,v3=0,v4=0;
        #pragma unroll
        for(int t=0;t<9;t++){
            int hc = h + t - 4;
            if(hc>=0 && hc<256){
                float gg = g[t]*inv;
                size_t base = (size_t)m*5*HW + (size_t)hc*256 + w;
                v0+=gg*tmp[base]; v1+=gg*tmp[base+HW]; v2+=gg*tmp[base+2*(size_t)HW];
                v3+=gg*tmp[base+3*(size_t)HW]; v4+=gg*tmp[base+4*(size_t)HW];
            }
        }
        float mu1=v0, mu2=v1;
        float mu1s=mu1*mu1, mu2s=mu2*mu2, mu12=mu1*mu2;
        float sg1=v2-mu1s, sg2=v3-mu2s, sg12=v4-mu12;
        float num=(2.f*mu12+C1S)*(2.f*sg12+C2S);
        float den=(mu1s+mu2s+C1S)*(sg1+sg2+C2S);
        msum += num/den;
    }
    float ss = msum*(1.f/3.f);
    float d = fminf(fmaxf((1.f-ss)*0.5f,0.f),1.f);
    diff[pix] = d;
    regin[(size_t)pix*REGC + 281] = f2b(d);
}

// ---------------- 7) q,k 1x1 convs -> regin bf16, + fused l2-norm reduce ----------
__global__ void k_qk(const float* __restrict__ x31, const float* __restrict__ y,
                     const float* __restrict__ qw, const float* __restrict__ qb,
                     const float* __restrict__ kw, const float* __restrict__ kb,
                     u16* __restrict__ regin, float* __restrict__ qinv,
                     float* __restrict__ kinv){
    __shared__ float sqw[CE*CH];
    __shared__ float skw[CE*CM];
    __shared__ float sqb[CE], skb[CE];
    __shared__ float redq[4][2], redk[4][2];
    for(int i=threadIdx.x;i<CE*CH;i+=128) sqw[i]=qw[i];
    for(int i=threadIdx.x;i<CE*CM;i+=128) skw[i]=kw[i];
    if(threadIdx.x<CE){ sqb[threadIdx.x]=qb[threadIdx.x]; skb[threadIdx.x]=kb[threadIdx.x]; }
    __syncthreads();
    int co = threadIdx.x, wid = co>>6, lane = co&63;
    int p0 = blockIdx.x*4;
    for(int pp=0;pp<4;pp++){
        int pix = p0+pp;
        const float* xr = x31 + (size_t)pix*32;
        float acc = sqb[co];
        #pragma unroll
        for(int c=0;c<CH;c++) acc += sqw[co*CH+c]*xr[c];
        regin[(size_t)pix*REGC + co] = f2b(acc);
        float ack = skb[co];
        #pragma unroll
        for(int c=0;c<CM;c++) ack += skw[co*CM+c]*y[(size_t)c*HW + pix];
        regin[(size_t)pix*REGC + 128 + co] = f2b(ack);
        if(co<6) regin[(size_t)pix*REGC + 282 + co] = 0;  // zero channel pad
        // fused l2 norms (reduce over all 128 couts = 2 waves)
        float sq = acc*acc, sk2 = ack*ack;
        #pragma unroll
        for(int t=1;t<64;t<<=1){ sq += __shfl_xor(sq,t); sk2 += __shfl_xor(sk2,t); }
        if(lane==0){ redq[pp][wid]=sq; redk[pp][wid]=sk2; }
        __syncthreads();
        if(threadIdx.x==0)  qinv[pix] = 1.f/fmaxf(sqrtf(redq[pp][0]+redq[pp][1]),1e-12f);
        if(threadIdx.x==64) kinv[pix] = 1.f/fmaxf(sqrtf(redk[pp][0]+redk[pp][1]),1e-12f);
    }
}

// ---------------- 9) correlation volume: lane-pair per pixel ----------------------
__global__ __launch_bounds__(256) void k_corr(const u16* __restrict__ regin,
                                              const float* __restrict__ qinv,
                                              const float* __restrict__ kinv,
                                              u16* __restrict__ regout){
    int t = threadIdx.x;
    int half = t & 1, pidx = t >> 1;           // 128 pixels per block
    int bid = blockIdx.x;
    int tx = bid & 7, ty = bid >> 3;            // 8 x 64 grid
    int w = tx*32 + (pidx & 31);
    int h = ty*4 + (pidx >> 5);
    int pix = (h<<8) + w;

    uint4 q[8];
    const uint4* qp = (const uint4*)(regin + (size_t)pix*REGC) + half*8;
    #pragma unroll
    for(int i=0;i<8;i++) q[i] = qp[i];
    float qn = qinv[pix];

    #pragma unroll
    for(int dy=-2;dy<=2;dy++){
        int hc = min(max(h+dy,0),255);
        #pragma unroll
        for(int dx=-2;dx<=2;dx++){
            int wc = min(max(w+dx,0),255);
            int npix = (hc<<8)+wc;
            const uint4* kp = (const uint4*)(regin + (size_t)npix*REGC + 128) + half*8;
            float s = 0.f;
            #pragma unroll
            for(int i=0;i<8;i++){
                uint4 kv = kp[i];
                uint4 qv = q[i];
                s += blo(qv.x)*blo(kv.x) + bhi(qv.x)*bhi(kv.x);
                s += blo(qv.y)*blo(kv.y) + bhi(qv.y)*bhi(kv.y);
                s += blo(qv.z)*blo(kv.z) + bhi(qv.z)*bhi(kv.z);
                s += blo(qv.w)*blo(kv.w) + bhi(qv.w)*bhi(kv.w);
            }
            s += __shfl_xor(s, 1);              // merge channel halves
            int o = (dy+2)*5 + (dx+2);
            bool mine = half ? (o>=13) : (o<13);
            if(mine) regout[(size_t)pix*REGC + 256 + o] = f2b(s*qn*kinv[npix]);
        }
    }
}

// ---------------- 10) weight rearrange + zpad clear --------------------------------
__global__ void k_wre(const float* __restrict__ w1, const float* __restrict__ w2,
                      u16* __restrict__ w1f, u16* __restrict__ w2f,
                      u16* __restrict__ zpad){
    int i = blockIdx.x*256 + threadIdx.x;
    if(i < 32) zpad[i] = 0;                       // 64B zero source for halo DMA
    if(i < 9*9*128*32){
        int j = i & 7;
        int gg = (i>>3)&3;
        int co = (i>>5)&127;
        int rest = i>>12;          // tap*9 + kbg
        int kbg = rest%9, tap = rest/9;
        int ci = kbg*32 + gg*8 + j;
        float v = (ci<282) ? w1[((size_t)co*282 + ci)*9 + tap] : 0.f;
        w1f[i] = f2b(v);
    }
    if(i < 9*4*64*32){
        int j = i & 7;
        int gg = (i>>3)&3;
        int co = (i>>5)&63;
        int rest = i>>11;          // tap*4 + kbg
        int kbg = rest&3, tap = rest>>2;
        int ci = kbg*32 + gg*8 + j;
        w2f[i] = f2b(w2[((size_t)co*128 + ci)*9 + tap]);
    }
}

// ---------------- 11+12) MFMA 3x3 conv (implicit GEMM over taps) -------------------
// Staging via global_load_lds: ALL lanes issue (halo lanes -> zpad source), so the
// wave-uniform LDS base is exact and writes are linear per lane.

__device__ __forceinline__ void lda4(const uint4* sbuf, int ky, int kx, int kb,
                                     int lane15, int lgrp, bf16x8* ar){
    #pragma unroll
    for(int mf=0;mf<4;mf++){
        int spx  = (mf&1)*16 + lane15 + kx;       // 0..33
        int srow = (mf>>1) + ky;                  // 0..3
        int slot = (srow*34 + spx)*8 + ((kb*4 + lgrp) ^ (spx&7));
        ar[mf] = *(const bf16x8*)&sbuf[slot];
    }
}

template<int NF, int KBGT, int NCO>
__device__ __forceinline__ void ldbN(const u16* __restrict__ wf, int kbg, int tap,
                                     int co0, int lane15, int lgrp, bf16x8* br){
    #pragma unroll
    for(int nf=0;nf<NF;nf++){
        size_t idx = ((size_t)((tap*KBGT + kbg)*NCO + co0 + nf*16 + lane15))*4 + lgrp;
        br[nf] = *(const bf16x8*)(wf + idx*8);
    }
}

template<int NF, int KBGT, int NCO, int KBI>
__device__ __forceinline__ void conv_steps(const uint4* sbuf, const u16* __restrict__ wf,
                                           int kbgbase, int co0, int lane15, int lgrp,
                                           f32x4 (&acc)[4][NF]){
    bf16x8 a[2][4];
    bf16x8 b[2][NF];
    lda4(sbuf, 0,0,0, lane15, lgrp, a[0]);
    ldbN<NF,KBGT,NCO>(wf, kbgbase, 0, co0, lane15, lgrp, b[0]);
    constexpr int NST = 9*KBI;
    #pragma unroll
    for(int s=0;s<NST;s++){
        int nx = s+1;
        if(nx < NST){
            int ky2,kx2,kb2;
            if(KBI==2){ ky2 = nx/6; kx2 = (nx>>1)%3; kb2 = nx&1; }
            else      { ky2 = nx/3; kx2 = nx%3;      kb2 = 0;   }
            lda4(sbuf, ky2,kx2,kb2, lane15, lgrp, a[nx&1]);
            ldbN<NF,KBGT,NCO>(wf, kbgbase+kb2, ky2*3+kx2, co0, lane15, lgrp, b[nx&1]);
        }
        #pragma unroll
        for(int mf=0;mf<4;mf++)
            #pragma unroll
            for(int nf=0;nf<NF;nf++)
                acc[mf][nf] = mfma16(a[s&1][mf], b[s&1][nf], acc[mf][nf]);
    }
}

template<int CSTRIDE, int CINTOT, int NCO, int KBGT, int NW>
__global__ __launch_bounds__(NW*64, 2) void k_conv3(const u16* __restrict__ in,
                                                    const u16* __restrict__ wf,
                                                    const float* __restrict__ bias,
                                                    u16* __restrict__ out,
                                                    const u16* __restrict__ zpad){
    constexpr int NF = NCO/(16*NW);
    constexpr int NCHUNK = (CINTOT + 63)/64;
    constexpr int NTH = NW*64;
    __shared__ uint4 sT[2*1088];
    int t = threadIdx.x;
    int lane15 = t & 15, lgrp = (t >> 4) & 3;
    int co0 = (t >> 6) * (NCO/NW);
    int bid = blockIdx.x;
    int tx = bid & 7, ty = bid >> 3;
    int row0 = ty*2, col0 = tx*32;

    f32x4 acc[4][NF];
    #pragma unroll
    for(int nf=0;nf<NF;nf++){
        float bsv = bias[co0 + nf*16 + lane15];
        #pragma unroll
        for(int mf=0;mf<4;mf++) acc[mf][nf] = f32x4{bsv,bsv,bsv,bsv};
    }

    // stage one 64-channel chunk: slot s holds data(srow,spx, gg=slot_g^(spx&7)).
    // Every lane issues the DMA (halo -> zpad) so LDS writes stay linear.
    auto stage = [&](int buf, int kc){
        constexpr int NIT = (1088 + NTH - 1)/NTH;   // 9 (NW=2) or 17 (NW=1)
        #pragma unroll
        for(int it=0; it<NIT; ++it){
            int s = it*NTH + t;
            if(NTH==128 && it==NIT-1 && t>=64) continue;  // whole wave off: safe
            int srow = s/272, rem = s - srow*272;
            int spx = rem>>3, ggp = rem&7;
            int gg = ggp ^ (spx&7);
            int gy = row0-1+srow, gx = col0-1+spx;
            bool ok = ((unsigned)gy<256u) && ((unsigned)gx<256u);
            const u16* src = ok ? (in + (size_t)((gy<<8)+gx)*CSTRIDE + kc + gg*8) : zpad;
            __builtin_amdgcn_global_load_lds(
                (const __attribute__((address_space(1))) u32*)src,
                (__attribute__((address_space(3))) u32*)&sT[buf*1088 + s],
                16, 0, 0);
        }
    };

    stage(0, 0);
    if(NW==2) __syncthreads();
    else      asm volatile("s_waitcnt vmcnt(0)" ::: "memory");

    int cur = 0;
    for(int j=0;j<NCHUNK;j++){
        if(j+1 < NCHUNK) stage(cur^1, (j+1)*64);
        if(CINTOT==288 && j==NCHUNK-1)
            conv_steps<NF,KBGT,NCO,1>(&sT[cur*1088], wf, j*2, co0, lane15, lgrp, acc);
        else
            conv_steps<NF,KBGT,NCO,2>(&sT[cur*1088], wf, j*2, co0, lane15, lgrp, acc);
        if(j+1 < NCHUNK){
            if(NW==2) __syncthreads();
            else      asm volatile("s_waitcnt vmcnt(0)" ::: "memory");
            cur ^= 1;
        }
    }

    // epilogue: leaky_relu + bf16 store. D frag: col(lane&15)=co, row=(lane>>4)*4+r = px
    #pragma unroll
    for(int mf=0;mf<4;mf++){
        int prow  = row0 + (mf>>1);
        int pcolb = col0 + (mf&1)*16 + lgrp*4;
        #pragma unroll
        for(int nf=0;nf<NF;nf++){
            int co = co0 + nf*16 + lane15;
            #pragma unroll
            for(int r=0;r<4;r++){
                int pix = (prow<<8) + pcolb + r;
                float v = acc[mf][nf][r];
                v = (v>0.f) ? v : 0.2f*v;
                out[(size_t)pix*NCO + co] = f2b(v);
            }
        }
    }
}

// ---------------- 13) flow (1x1 conv + tanh) + bilinear warp -----------------------
__device__ __forceinline__ float reflectc(float coord, float size){
    float c = fabsf(coord + 0.5f);
    float extra = fmodf(c, size);
    float flips = floorf(c/size);
    float fo = fmodf(flips, 2.0f);
    float r = (fo == 0.0f) ? (extra - 0.5f) : (size - extra - 0.5f);
    return fminf(fmaxf(r, 0.0f), size - 1.0f);
}

__global__ void k_flowwarp(const u16* __restrict__ h2, const float* __restrict__ w3,
                           const float* __restrict__ b3, const float* __restrict__ diff,
                           const float* __restrict__ x31, float* __restrict__ out){
    __shared__ float sw[130];
    for(int i=threadIdx.x;i<128;i+=256) sw[i]=w3[i];
    if(threadIdx.x<2) sw[128+threadIdx.x]=b3[threadIdx.x];
    __syncthreads();
    int pix = blockIdx.x*256 + threadIdx.x;
    if(pix>=HW) return;
    int h = pix>>8, w = pix&255;
    const uint4* h4 = (const uint4*)(h2 + (size_t)pix*64);
    float f0 = sw[128], f1 = sw[129];
    #pragma unroll
    for(int cc=0;cc<8;cc++){
        uint4 u = h4[cc];
        float vv[8] = {blo(u.x),bhi(u.x),blo(u.y),bhi(u.y),blo(u.z),bhi(u.z),blo(u.w),bhi(u.w)};
        #pragma unroll
        for(int j=0;j<8;j++){ int c = cc*8+j; f0 += sw[c]*vv[j]; f1 += sw[64+c]*vv[j]; }
    }
    float d = diff[pix];
    f0 = tanhf(f0)*2.0f*d;
    f1 = tanhf(f1)*2.0f*d;
    float ix = reflectc((float)w + f0, 256.f);
    float iy = reflectc((float)h + f1, 256.f);
    float x0 = floorf(ix), y0 = floorf(iy);
    float wx = ix-x0, wy = iy-y0;
    int x0i = min(max((int)x0,0),255);
    int x1i = min(x0i+1,255);
    int y0i = min(max((int)y0,0),255);
    int y1i = min(y0i+1,255);
    const float* p00 = x31 + ((size_t)((y0i<<8)+x0i))*32;
    const float* p01 = x31 + ((size_t)((y0i<<8)+x1i))*32;
    const float* p10 = x31 + ((size_t)((y1i<<8)+x0i))*32;
    const float* p11 = x31 + ((size_t)((y1i<<8)+x1i))*32;
    float w00=(1.f-wy)*(1.f-wx), w01=(1.f-wy)*wx, w10=wy*(1.f-wx), w11=wy*wx;
    float* ob = out + pix;
    #pragma unroll
    for(int c=0;c<CH;c++){
        ob[(size_t)c*HW] = w00*p00[c] + w01*p01[c] + w10*p10[c] + w11*p11[c];
    }
}

extern "C" void kernel_launch(void* const* d_in, const int* in_sizes, int n_in,
                              void* d_out, int out_size, void* d_ws, size_t ws_size,
                              hipStream_t stream) {
    const float* x    = (const float*)d_in[0];
    const float* y    = (const float*)d_in[1];
    const float* srf  = (const float*)d_in[2];
    const float* chw  = (const float*)d_in[3];
    const float* chb  = (const float*)d_in[4];
    const float* qw   = (const float*)d_in[5];
    const float* qb   = (const float*)d_in[6];
    const float* kw   = (const float*)d_in[7];
    const float* kb   = (const float*)d_in[8];
    const float* w1   = (const float*)d_in[9];
    const float* b1p  = (const float*)d_in[10];
    const float* w2   = (const float*)d_in[11];
    const float* b2p  = (const float*)d_in[12];
    const float* w3   = (const float*)d_in[13];
    const float* b3p  = (const float*)d_in[14];

    // Per-batch workspace (reused across b=0..3): ~78 MB total.
    char* ws = (char*)d_ws;
    size_t o = 0;
    float* x31   = (float*)(ws+o); o += (size_t)HW*32*4;       //  8.4 MB
    float* xp    = (float*)(ws+o); o += (size_t)3*HW*4;        //  0.8 MB
    float* xa    = (float*)(ws+o); o += (size_t)3*HW*4;        //  0.8 MB
    float* stats = (float*)(ws+o); o += 256;
    float* tmp   = (float*)(ws+o); o += (size_t)15*HW*4;       //  3.9 MB
    float* diff  = (float*)(ws+o); o += (size_t)HW*4;          //  0.3 MB
    float* qinv  = (float*)(ws+o); o += (size_t)HW*4;
    float* kinv  = (float*)(ws+o); o += (size_t)HW*4;
    u16* regin   = (u16*)(ws+o);   o += (size_t)HW*REGC*2;     // 37.7 MB
    u16* h1      = (u16*)(ws+o);   o += (size_t)HW*128*2;      // 16.8 MB
    u16* h2      = (u16*)(ws+o);   o += (size_t)HW*64*2;       //  8.4 MB
    u16* w1f     = (u16*)(ws+o);   o += (size_t)9*9*128*32*2;  //  0.66 MB
    u16* w2f     = (u16*)(ws+o);   o += (size_t)9*4*64*32*2;   //  0.15 MB
    u16* zpad    = (u16*)(ws+o);   o += 64;                    //  64 B zero source

    k_wre<<<1296, 256, 0, stream>>>(w1, w2, w1f, w2f, zpad);

    for(int b=0;b<4;b++){
        const float* xb  = x + (size_t)b*CIN2*HW;
        const float* yb  = y + (size_t)b*CM*HW;
        float* outb      = (float*)d_out + (size_t)b*CH*HW;

        k_conv_half<<<256,  256, 0, stream>>>(xb, chw, chb, x31);
        k_project  <<<256,  256, 0, stream>>>(x31, srf, xp);
        k_stats    <<<6,    256, 0, stream>>>(xp, yb, stats);
        k_align    <<<768,  256, 0, stream>>>(xp, stats, xa);
        k_ssim_h   <<<768,  256, 0, stream>>>(xa, yb, tmp);
        k_ssim_v   <<<256,  256, 0, stream>>>(tmp, diff, regin);
        k_qk       <<<16384,128, 0, stream>>>(x31, yb, qw, qb, kw, kb, regin, qinv, kinv);
        k_corr     <<<512,  256, 0, stream>>>(regin, qinv, kinv, regin);
        k_conv3<288,288,128,9,2><<<1024, 128, 0, stream>>>(regin, w1f, b1p, h1, zpad);
        k_conv3<128,128, 64,4,1><<<1024,  64, 0, stream>>>(h1, w2f, b2p, h2, zpad);
        k_flowwarp <<<256,  256, 0, stream>>>(h2, w3, b3p, diff, x31, outb);
    }
}

// Round 7
// 1097.948 us; speedup vs baseline: 5.8573x; 1.2131x over previous
//
#include <hip/hip_runtime.h>
#include <hip/hip_bf16.h>
#include <math.h>

// Per-batch pipeline; r1/r2 are MFMA implicit-GEMM convs.
// R7: k_stats -> two-stage parallel reduction (was 6-block latency-bound serial
// scan: 107us/dispatch at 0.2% occupancy = 32% of total runtime).

#define HH 256
#define WWI 256
#define HW 65536
#define CH 31
#define CIN2 62
#define CM 3
#define CE 128
#define REGC 288
#define C1S 1e-4f
#define C2S 9e-4f

typedef unsigned short u16;
typedef unsigned int u32;
typedef short bf16x8 __attribute__((ext_vector_type(8)));   // 8 bf16 in 4 VGPRs
typedef float f32x4 __attribute__((ext_vector_type(4)));

__device__ __forceinline__ float blo(u32 u){ return __uint_as_float(u << 16); }
__device__ __forceinline__ float bhi(u32 u){ return __uint_as_float(u & 0xffff0000u); }
__device__ __forceinline__ float b1f(u16 u){ return __uint_as_float(((u32)u) << 16); }
__device__ __forceinline__ u16 f2b(float f){
    u32 u = __float_as_uint(f);
    u32 r = (u + 0x7fffu + ((u >> 16) & 1u)) >> 16;
    return (u16)r;
}
__device__ __forceinline__ f32x4 mfma16(bf16x8 a, bf16x8 b, f32x4 c){
    return __builtin_amdgcn_mfma_f32_16x16x32_bf16(a, b, c, 0, 0, 0);
}

// ---------------- 1) conv_half (one batch): (62,H,W) f32 -> x31 NHWC f32 [pix][32]
__global__ void k_conv_half(const float* __restrict__ x, const float* __restrict__ w,
                            const float* __restrict__ bias, float* __restrict__ x31){
    __shared__ float sw[CH*CIN2];
    __shared__ float sb[CH+1];
    for(int i=threadIdx.x;i<CH*CIN2;i+=256) sw[i]=w[i];
    for(int i=threadIdx.x;i<CH;i+=256) sb[i]=bias[i];
    __syncthreads();
    int pix = blockIdx.x*256 + threadIdx.x;
    if(pix>=HW) return;
    float acc[CH];
    #pragma unroll
    for(int c=0;c<CH;c++) acc[c]=sb[c];
    for(int ci=0;ci<CIN2;ci++){
        float xv = x[(size_t)ci*HW + pix];
        #pragma unroll
        for(int c=0;c<CH;c++) acc[c] += sw[c*CIN2+ci]*xv;
    }
    float* o = x31 + (size_t)pix*32;
    #pragma unroll
    for(int c=0;c<CH;c++) o[c]=acc[c];
    o[31]=0.f;
}

// ---------------- 2) project: xp = clip(SRF @ x31, -1, 1), layout [3][HW] --------
__global__ void k_project(const float* __restrict__ x31, const float* __restrict__ srf,
                          float* __restrict__ xp){
    __shared__ float s[CM*CH];
    for(int i=threadIdx.x;i<CM*CH;i+=256) s[i]=srf[i];
    __syncthreads();
    int pix = blockIdx.x*256 + threadIdx.x;
    if(pix>=HW) return;
    const float* xr = x31 + (size_t)pix*32;
    #pragma unroll
    for(int m=0;m<CM;m++){
        float acc=0.f;
        #pragma unroll
        for(int c=0;c<CH;c++) acc += s[m*CH+c]*xr[c];
        acc = fminf(fmaxf(acc,-1.f),1.f);
        xp[(size_t)m*HW + pix] = acc;
    }
}

// ---------------- 3a) stats stage 1: per-chunk partial sums ------------------------
// grid 384 = 6 planes x 64 chunks; block 256 thr; each thread reads float4.
__global__ void k_stats1(const float* __restrict__ xp, const float* __restrict__ y,
                         float2* __restrict__ part){
    int bid = blockIdx.x;
    int p = bid >> 6, c = bid & 63;
    const float* src = (p<3) ? (xp + (size_t)p*HW) : (y + (size_t)(p-3)*HW);
    const float4* s4 = (const float4*)(src + c*1024);
    float4 v = s4[threadIdx.x];
    float s  = v.x + v.y + v.z + v.w;
    float ss = v.x*v.x + v.y*v.y + v.z*v.z + v.w*v.w;
    #pragma unroll
    for(int t=1;t<64;t<<=1){ s += __shfl_xor(s,t); ss += __shfl_xor(ss,t); }
    __shared__ float rs[4], rss[4];
    int wid = threadIdx.x>>6, lane = threadIdx.x&63;
    if(lane==0){ rs[wid]=s; rss[wid]=ss; }
    __syncthreads();
    if(threadIdx.x==0){
        part[bid] = float2{rs[0]+rs[1]+rs[2]+rs[3], rss[0]+rss[1]+rss[2]+rss[3]};
    }
}

// ---------------- 3b) stats stage 2: combine 64 partials -> mean/std(ddof=1) ------
__global__ void k_stats2(const float2* __restrict__ part, float* __restrict__ stats){
    int p = blockIdx.x;                 // 6 planes
    float2 pa = part[p*64 + threadIdx.x];
    float s = pa.x, ss = pa.y;
    #pragma unroll
    for(int t=1;t<64;t<<=1){ s += __shfl_xor(s,t); ss += __shfl_xor(ss,t); }
    if(threadIdx.x==0){
        float mean = s/(float)HW;
        float var = (ss - s*s/(float)HW) / (float)(HW-1);
        stats[p*2]   = mean;
        stats[p*2+1] = sqrtf(fmaxf(var,0.f));
    }
}

// ---------------- 4) align ---------------------------------------------------------
__global__ void k_align(const float* __restrict__ xp, const float* __restrict__ stats,
                        float* __restrict__ xa){
    int i = blockIdx.x*256 + threadIdx.x;
    if(i>=3*HW) return;
    int plane = i>>16;
    float sm = stats[plane*2], ssd = stats[plane*2+1];
    float rm = stats[(plane+3)*2], rsd = stats[(plane+3)*2+1];
    float v = (xp[i]-sm)/(ssd+1e-6f)*rsd + rm;
    xa[i] = fminf(fmaxf(v,-1.f),1.f);
}

// ---------------- 5) ssim horizontal gaussian pass ---------------------------------
__global__ void k_ssim_h(const float* __restrict__ xa, const float* __restrict__ y,
                         float* __restrict__ tmp){
    int i = blockIdx.x*256 + threadIdx.x;
    if(i>=3*HW) return;
    int plane = i>>16, hw = i&65535, h = hw>>8, w = hw&255;
    float g[9]; float gs=0.f;
    #pragma unroll
    for(int t=0;t<9;t++){ float cc=(float)(t-4); g[t]=expf(-cc*cc/4.5f); gs+=g[t]; }
    float inv = 1.f/gs;
    float s0=0,s1=0,s2=0,s3=0,s4=0;
    const float* xr = xa + (size_t)plane*HW + (size_t)h*256;
    const float* yr = y  + (size_t)plane*HW + (size_t)h*256;
    #pragma unroll
    for(int t=0;t<9;t++){
        int wc = w + t - 4;
        if(wc>=0 && wc<256){
            float gg = g[t]*inv;
            float a = xr[wc], b = yr[wc];
            s0+=gg*a; s1+=gg*b; s2+=gg*a*a; s3+=gg*b*b; s4+=gg*a*b;
        }
    }
    size_t base = (size_t)plane*5*HW + hw;
    tmp[base]=s0; tmp[base+HW]=s1; tmp[base+2*(size_t)HW]=s2; tmp[base+3*(size_t)HW]=s3; tmp[base+4*(size_t)HW]=s4;
}

// ---------------- 6) ssim vertical pass + difficulty -> diff, regin ch281 ---------
__global__ void k_ssim_v(const float* __restrict__ tmp, float* __restrict__ diff,
                         u16* __restrict__ regin){
    int pix = blockIdx.x*256 + threadIdx.x;
    if(pix>=HW) return;
    int h = pix>>8, w = pix&255;
    float g[9]; float gs=0.f;
    #pragma unroll
    for(int t=0;t<9;t++){ float cc=(float)(t-4); g[t]=expf(-cc*cc/4.5f); gs+=g[t]; }
    float inv = 1.f/gs;
    float msum = 0.f;
    for(int m=0;m<3;m++){
        float v0=0,v1=0,v2=0,v3=0,v4=0;
        #pragma unroll
        for(int t=0;t<9;t++){
            int hc = h + t - 4;
            if(hc>=0 && hc<256){
                float gg = g[t]*inv;
                size_t base = (size_t)m*5*HW + (size_t)hc*256 + w;
                v0+=gg*tmp[base]; v1+=gg*tmp[base+HW]; v2+=gg*tmp[base+2*(size_t)HW];
                v3+=gg*tmp[base+3*(size_t)HW]; v4+=gg*tmp[base+4*(size_t)HW];
            }
        }
        float mu1=v0, mu2=v1;
        float mu1s=mu1*mu1, mu2s=mu2*mu2, mu12=mu1*mu2;
        float sg1=v2-mu1s, sg2=v3-mu2s, sg12=v4-mu12;
        float num=(2.f*mu12+C1S)*(2.f*sg12+C2S);
        float den=(mu1s+mu2s+C1S)*(sg1+sg2+C2S);
        msum += num/den;
    }
    float ss = msum*(1.f/3.f);
    float d = fminf(fmaxf((1.f-ss)*0.5f,0.f),1.f);
    diff[pix] = d;
    regin[(size_t)pix*REGC + 281] = f2b(d);
}

// ---------------- 7) q,k 1x1 convs -> regin bf16, + fused l2-norm reduce ----------
__global__ void k_qk(const float* __restrict__ x31, const float* __restrict__ y,
                     const float* __restrict__ qw, const float* __restrict__ qb,
                     const float* __restrict__ kw, const float* __restrict__ kb,
                     u16* __restrict__ regin, float* __restrict__ qinv,
                     float* __restrict__ kinv){
    __shared__ float sqw[CE*CH];
    __shared__ float skw[CE*CM];
    __shared__ float sqb[CE], skb[CE];
    __shared__ float redq[4][2], redk[4][2];
    for(int i=threadIdx.x;i<CE*CH;i+=128) sqw[i]=qw[i];
    for(int i=threadIdx.x;i<CE*CM;i+=128) skw[i]=kw[i];
    if(threadIdx.x<CE){ sqb[threadIdx.x]=qb[threadIdx.x]; skb[threadIdx.x]=kb[threadIdx.x]; }
    __syncthreads();
    int co = threadIdx.x, wid = co>>6, lane = co&63;
    int p0 = blockIdx.x*4;
    for(int pp=0;pp<4;pp++){
        int pix = p0+pp;
        const float* xr = x31 + (size_t)pix*32;
        float acc = sqb[co];
        #pragma unroll
        for(int c=0;c<CH;c++) acc += sqw[co*CH+c]*xr[c];
        regin[(size_t)pix*REGC + co] = f2b(acc);
        float ack = skb[co];
        #pragma unroll
        for(int c=0;c<CM;c++) ack += skw[co*CM+c]*y[(size_t)c*HW + pix];
        regin[(size_t)pix*REGC + 128 + co] = f2b(ack);
        if(co<6) regin[(size_t)pix*REGC + 282 + co] = 0;  // zero channel pad
        // fused l2 norms (reduce over all 128 couts = 2 waves)
        float sq = acc*acc, sk2 = ack*ack;
        #pragma unroll
        for(int t=1;t<64;t<<=1){ sq += __shfl_xor(sq,t); sk2 += __shfl_xor(sk2,t); }
        if(lane==0){ redq[pp][wid]=sq; redk[pp][wid]=sk2; }
        __syncthreads();
        if(threadIdx.x==0)  qinv[pix] = 1.f/fmaxf(sqrtf(redq[pp][0]+redq[pp][1]),1e-12f);
        if(threadIdx.x==64) kinv[pix] = 1.f/fmaxf(sqrtf(redk[pp][0]+redk[pp][1]),1e-12f);
    }
}

// ---------------- 9) correlation volume: lane-pair per pixel ----------------------
__global__ __launch_bounds__(256) void k_corr(const u16* __restrict__ regin,
                                              const float* __restrict__ qinv,
                                              const float* __restrict__ kinv,
                                              u16* __restrict__ regout){
    int t = threadIdx.x;
    int half = t & 1, pidx = t >> 1;           // 128 pixels per block
    int bid = blockIdx.x;
    int tx = bid & 7, ty = bid >> 3;            // 8 x 64 grid
    int w = tx*32 + (pidx & 31);
    int h = ty*4 + (pidx >> 5);
    int pix = (h<<8) + w;

    uint4 q[8];
    const uint4* qp = (const uint4*)(regin + (size_t)pix*REGC) + half*8;
    #pragma unroll
    for(int i=0;i<8;i++) q[i] = qp[i];
    float qn = qinv[pix];

    #pragma unroll
    for(int dy=-2;dy<=2;dy++){
        int hc = min(max(h+dy,0),255);
        #pragma unroll
        for(int dx=-2;dx<=2;dx++){
            int wc = min(max(w+dx,0),255);
            int npix = (hc<<8)+wc;
            const uint4* kp = (const uint4*)(regin + (size_t)npix*REGC + 128) + half*8;
            float s = 0.f;
            #pragma unroll
            for(int i=0;i<8;i++){
                uint4 kv = kp[i];
                uint4 qv = q[i];
                s += blo(qv.x)*blo(kv.x) + bhi(qv.x)*bhi(kv.x);
                s += blo(qv.y)*blo(kv.y) + bhi(qv.y)*bhi(kv.y);
                s += blo(qv.z)*blo(kv.z) + bhi(qv.z)*bhi(kv.z);
                s += blo(qv.w)*blo(kv.w) + bhi(qv.w)*bhi(kv.w);
            }
            s += __shfl_xor(s, 1);              // merge channel halves
            int o = (dy+2)*5 + (dx+2);
            bool mine = half ? (o>=13) : (o<13);
            if(mine) regout[(size_t)pix*REGC + 256 + o] = f2b(s*qn*kinv[npix]);
        }
    }
}

// ---------------- 10) weight rearrange + zpad clear --------------------------------
__global__ void k_wre(const float* __restrict__ w1, const float* __restrict__ w2,
                      u16* __restrict__ w1f, u16* __restrict__ w2f,
                      u16* __restrict__ zpad){
    int i = blockIdx.x*256 + threadIdx.x;
    if(i < 32) zpad[i] = 0;                       // 64B zero source for halo DMA
    if(i < 9*9*128*32){
        int j = i & 7;
        int gg = (i>>3)&3;
        int co = (i>>5)&127;
        int rest = i>>12;          // tap*9 + kbg
        int kbg = rest%9, tap = rest/9;
        int ci = kbg*32 + gg*8 + j;
        float v = (ci<282) ? w1[((size_t)co*282 + ci)*9 + tap] : 0.f;
        w1f[i] = f2b(v);
    }
    if(i < 9*4*64*32){
        int j = i & 7;
        int gg = (i>>3)&3;
        int co = (i>>5)&63;
        int rest = i>>11;          // tap*4 + kbg
        int kbg = rest&3, tap = rest>>2;
        int ci = kbg*32 + gg*8 + j;
        w2f[i] = f2b(w2[((size_t)co*128 + ci)*9 + tap]);
    }
}

// ---------------- 11+12) MFMA 3x3 conv (implicit GEMM over taps) -------------------
__device__ __forceinline__ void lda4(const uint4* sbuf, int ky, int kx, int kb,
                                     int lane15, int lgrp, bf16x8* ar){
    #pragma unroll
    for(int mf=0;mf<4;mf++){
        int spx  = (mf&1)*16 + lane15 + kx;       // 0..33
        int srow = (mf>>1) + ky;                  // 0..3
        int slot = (srow*34 + spx)*8 + ((kb*4 + lgrp) ^ (spx&7));
        ar[mf] = *(const bf16x8*)&sbuf[slot];
    }
}

template<int NF, int KBGT, int NCO>
__device__ __forceinline__ void ldbN(const u16* __restrict__ wf, int kbg, int tap,
                                     int co0, int lane15, int lgrp, bf16x8* br){
    #pragma unroll
    for(int nf=0;nf<NF;nf++){
        size_t idx = ((size_t)((tap*KBGT + kbg)*NCO + co0 + nf*16 + lane15))*4 + lgrp;
        br[nf] = *(const bf16x8*)(wf + idx*8);
    }
}

template<int NF, int KBGT, int NCO, int KBI>
__device__ __forceinline__ void conv_steps(const uint4* sbuf, const u16* __restrict__ wf,
                                           int kbgbase, int co0, int lane15, int lgrp,
                                           f32x4 (&acc)[4][NF]){
    bf16x8 a[2][4];
    bf16x8 b[2][NF];
    lda4(sbuf, 0,0,0, lane15, lgrp, a[0]);
    ldbN<NF,KBGT,NCO>(wf, kbgbase, 0, co0, lane15, lgrp, b[0]);
    constexpr int NST = 9*KBI;
    #pragma unroll
    for(int s=0;s<NST;s++){
        int nx = s+1;
        if(nx < NST){
            int ky2,kx2,kb2;
            if(KBI==2){ ky2 = nx/6; kx2 = (nx>>1)%3; kb2 = nx&1; }
            else      { ky2 = nx/3; kx2 = nx%3;      kb2 = 0;   }
            lda4(sbuf, ky2,kx2,kb2, lane15, lgrp, a[nx&1]);
            ldbN<NF,KBGT,NCO>(wf, kbgbase+kb2, ky2*3+kx2, co0, lane15, lgrp, b[nx&1]);
        }
        #pragma unroll
        for(int mf=0;mf<4;mf++)
            #pragma unroll
            for(int nf=0;nf<NF;nf++)
                acc[mf][nf] = mfma16(a[s&1][mf], b[s&1][nf], acc[mf][nf]);
    }
}

template<int CSTRIDE, int CINTOT, int NCO, int KBGT, int NW>
__global__ __launch_bounds__(NW*64, 2) void k_conv3(const u16* __restrict__ in,
                                                    const u16* __restrict__ wf,
                                                    const float* __restrict__ bias,
                                                    u16* __restrict__ out,
                                                    const u16* __restrict__ zpad){
    constexpr int NF = NCO/(16*NW);
    constexpr int NCHUNK = (CINTOT + 63)/64;
    constexpr int NTH = NW*64;
    __shared__ uint4 sT[2*1088];
    int t = threadIdx.x;
    int lane15 = t & 15, lgrp = (t >> 4) & 3;
    int co0 = (t >> 6) * (NCO/NW);
    int bid = blockIdx.x;
    int tx = bid & 7, ty = bid >> 3;
    int row0 = ty*2, col0 = tx*32;

    f32x4 acc[4][NF];
    #pragma unroll
    for(int nf=0;nf<NF;nf++){
        float bsv = bias[co0 + nf*16 + lane15];
        #pragma unroll
        for(int mf=0;mf<4;mf++) acc[mf][nf] = f32x4{bsv,bsv,bsv,bsv};
    }

    auto stage = [&](int buf, int kc){
        constexpr int NIT = (1088 + NTH - 1)/NTH;   // 9 (NW=2) or 17 (NW=1)
        #pragma unroll
        for(int it=0; it<NIT; ++it){
            int s = it*NTH + t;
            if(NTH==128 && it==NIT-1 && t>=64) continue;  // whole wave off: safe
            int srow = s/272, rem = s - srow*272;
            int spx = rem>>3, ggp = rem&7;
            int gg = ggp ^ (spx&7);
            int gy = row0-1+srow, gx = col0-1+spx;
            bool ok = ((unsigned)gy<256u) && ((unsigned)gx<256u);
            const u16* src = ok ? (in + (size_t)((gy<<8)+gx)*CSTRIDE + kc + gg*8) : zpad;
            __builtin_amdgcn_global_load_lds(
                (const __attribute__((address_space(1))) u32*)src,
                (__attribute__((address_space(3))) u32*)&sT[buf*1088 + s],
                16, 0, 0);
        }
    };

    stage(0, 0);
    if(NW==2) __syncthreads();
    else      asm volatile("s_waitcnt vmcnt(0)" ::: "memory");

    int cur = 0;
    for(int j=0;j<NCHUNK;j++){
        if(j+1 < NCHUNK) stage(cur^1, (j+1)*64);
        if(CINTOT==288 && j==NCHUNK-1)
            conv_steps<NF,KBGT,NCO,1>(&sT[cur*1088], wf, j*2, co0, lane15, lgrp, acc);
        else
            conv_steps<NF,KBGT,NCO,2>(&sT[cur*1088], wf, j*2, co0, lane15, lgrp, acc);
        if(j+1 < NCHUNK){
            if(NW==2) __syncthreads();
            else      asm volatile("s_waitcnt vmcnt(0)" ::: "memory");
            cur ^= 1;
        }
    }

    #pragma unroll
    for(int mf=0;mf<4;mf++){
        int prow  = row0 + (mf>>1);
        int pcolb = col0 + (mf&1)*16 + lgrp*4;
        #pragma unroll
        for(int nf=0;nf<NF;nf++){
            int co = co0 + nf*16 + lane15;
            #pragma unroll
            for(int r=0;r<4;r++){
                int pix = (prow<<8) + pcolb + r;
                float v = acc[mf][nf][r];
                v = (v>0.f) ? v : 0.2f*v;
                out[(size_t)pix*NCO + co] = f2b(v);
            }
        }
    }
}

// ---------------- 13) flow (1x1 conv + tanh) + bilinear warp -----------------------
__device__ __forceinline__ float reflectc(float coord, float size){
    float c = fabsf(coord + 0.5f);
    float extra = fmodf(c, size);
    float flips = floorf(c/size);
    float fo = fmodf(flips, 2.0f);
    float r = (fo == 0.0f) ? (extra - 0.5f) : (size - extra - 0.5f);
    return fminf(fmaxf(r, 0.0f), size - 1.0f);
}

__global__ void k_flowwarp(const u16* __restrict__ h2, const float* __restrict__ w3,
                           const float* __restrict__ b3, const float* __restrict__ diff,
                           const float* __restrict__ x31, float* __restrict__ out){
    __shared__ float sw[130];
    for(int i=threadIdx.x;i<128;i+=256) sw[i]=w3[i];
    if(threadIdx.x<2) sw[128+threadIdx.x]=b3[threadIdx.x];
    __syncthreads();
    int pix = blockIdx.x*256 + threadIdx.x;
    if(pix>=HW) return;
    int h = pix>>8, w = pix&255;
    const uint4* h4 = (const uint4*)(h2 + (size_t)pix*64);
    float f0 = sw[128], f1 = sw[129];
    #pragma unroll
    for(int cc=0;cc<8;cc++){
        uint4 u = h4[cc];
        float vv[8] = {blo(u.x),bhi(u.x),blo(u.y),bhi(u.y),blo(u.z),bhi(u.z),blo(u.w),bhi(u.w)};
        #pragma unroll
        for(int j=0;j<8;j++){ int c = cc*8+j; f0 += sw[c]*vv[j]; f1 += sw[64+c]*vv[j]; }
    }
    float d = diff[pix];
    f0 = tanhf(f0)*2.0f*d;
    f1 = tanhf(f1)*2.0f*d;
    float ix = reflectc((float)w + f0, 256.f);
    float iy = reflectc((float)h + f1, 256.f);
    float x0 = floorf(ix), y0 = floorf(iy);
    float wx = ix-x0, wy = iy-y0;
    int x0i = min(max((int)x0,0),255);
    int x1i = min(x0i+1,255);
    int y0i = min(max((int)y0,0),255);
    int y1i = min(y0i+1,255);
    const float* p00 = x31 + ((size_t)((y0i<<8)+x0i))*32;
    const float* p01 = x31 + ((size_t)((y0i<<8)+x1i))*32;
    const float* p10 = x31 + ((size_t)((y1i<<8)+x0i))*32;
    const float* p11 = x31 + ((size_t)((y1i<<8)+x1i))*32;
    float w00=(1.f-wy)*(1.f-wx), w01=(1.f-wy)*wx, w10=wy*(1.f-wx), w11=wy*wx;
    float* ob = out + pix;
    #pragma unroll
    for(int c=0;c<CH;c++){
        ob[(size_t)c*HW] = w00*p00[c] + w01*p01[c] + w10*p10[c] + w11*p11[c];
    }
}

extern "C" void kernel_launch(void* const* d_in, const int* in_sizes, int n_in,
                              void* d_out, int out_size, void* d_ws, size_t ws_size,
                              hipStream_t stream) {
    const float* x    = (const float*)d_in[0];
    const float* y    = (const float*)d_in[1];
    const float* srf  = (const float*)d_in[2];
    const float* chw  = (const float*)d_in[3];
    const float* chb  = (const float*)d_in[4];
    const float* qw   = (const float*)d_in[5];
    const float* qb   = (const float*)d_in[6];
    const float* kw   = (const float*)d_in[7];
    const float* kb   = (const float*)d_in[8];
    const float* w1   = (const float*)d_in[9];
    const float* b1p  = (const float*)d_in[10];
    const float* w2   = (const float*)d_in[11];
    const float* b2p  = (const float*)d_in[12];
    const float* w3   = (const float*)d_in[13];
    const float* b3p  = (const float*)d_in[14];

    // Per-batch workspace (reused across b=0..3): ~78 MB total.
    char* ws = (char*)d_ws;
    size_t o = 0;
    float* x31   = (float*)(ws+o); o += (size_t)HW*32*4;       //  8.4 MB
    float* xp    = (float*)(ws+o); o += (size_t)3*HW*4;        //  0.8 MB
    float* xa    = (float*)(ws+o); o += (size_t)3*HW*4;        //  0.8 MB
    float* stats = (float*)(ws+o); o += 256;
    float2* part = (float2*)(ws+o);o += 384*sizeof(float2);
    float* tmp   = (float*)(ws+o); o += (size_t)15*HW*4;       //  3.9 MB
    float* diff  = (float*)(ws+o); o += (size_t)HW*4;          //  0.3 MB
    float* qinv  = (float*)(ws+o); o += (size_t)HW*4;
    float* kinv  = (float*)(ws+o); o += (size_t)HW*4;
    u16* regin   = (u16*)(ws+o);   o += (size_t)HW*REGC*2;     // 37.7 MB
    u16* h1      = (u16*)(ws+o);   o += (size_t)HW*128*2;      // 16.8 MB
    u16* h2      = (u16*)(ws+o);   o += (size_t)HW*64*2;       //  8.4 MB
    u16* w1f     = (u16*)(ws+o);   o += (size_t)9*9*128*32*2;  //  0.66 MB
    u16* w2f     = (u16*)(ws+o);   o += (size_t)9*4*64*32*2;   //  0.15 MB
    u16* zpad    = (u16*)(ws+o);   o += 64;                    //  64 B zero source

    k_wre<<<1296, 256, 0, stream>>>(w1, w2, w1f, w2f, zpad);

    for(int b=0;b<4;b++){
        const float* xb  = x + (size_t)b*CIN2*HW;
        const float* yb  = y + (size_t)b*CM*HW;
        float* outb      = (float*)d_out + (size_t)b*CH*HW;

        k_conv_half<<<256,  256, 0, stream>>>(xb, chw, chb, x31);
        k_project  <<<256,  256, 0, stream>>>(x31, srf, xp);
        k_stats1   <<<384,  256, 0, stream>>>(xp, yb, part);
        k_stats2   <<<6,     64, 0, stream>>>(part, stats);
        k_align    <<<768,  256, 0, stream>>>(xp, stats, xa);
        k_ssim_h   <<<768,  256, 0, stream>>>(xa, yb, tmp);
        k_ssim_v   <<<256,  256, 0, stream>>>(tmp, diff, regin);
        k_qk       <<<16384,128, 0, stream>>>(x31, yb, qw, qb, kw, kb, regin, qinv, kinv);
        k_corr     <<<512,  256, 0, stream>>>(regin, qinv, kinv, regin);
        k_conv3<288,288,128,9,2><<<1024, 128, 0, stream>>>(regin, w1f, b1p, h1, zpad);
        k_conv3<128,128, 64,4,1><<<1024,  64, 0, stream>>>(h1, w2f, b2p, h2, zpad);
        k_flowwarp <<<256,  256, 0, stream>>>(h2, w3, b3p, diff, x31, outb);
    }
}

// Round 8
// 1074.212 us; speedup vs baseline: 5.9867x; 1.0221x over previous
//
#include <hip/hip_runtime.h>
#include <hip/hip_bf16.h>
#include <math.h>

// Per-batch pipeline; r1/r2 are MFMA implicit-GEMM convs.
// R8: k_qk -> 32 px/block (8x weight-staging amortization), norms split into
// lane-pair k_norms kernel; k_conv3 r1 -> 4-wave blocks (16 waves/CU, was 8),
// r2 -> 2-wave blocks.

#define HH 256
#define WWI 256
#define HW 65536
#define CH 31
#define CIN2 62
#define CM 3
#define CE 128
#define REGC 288
#define C1S 1e-4f
#define C2S 9e-4f

typedef unsigned short u16;
typedef unsigned int u32;
typedef short bf16x8 __attribute__((ext_vector_type(8)));   // 8 bf16 in 4 VGPRs
typedef float f32x4 __attribute__((ext_vector_type(4)));

__device__ __forceinline__ float blo(u32 u){ return __uint_as_float(u << 16); }
__device__ __forceinline__ float bhi(u32 u){ return __uint_as_float(u & 0xffff0000u); }
__device__ __forceinline__ float b1f(u16 u){ return __uint_as_float(((u32)u) << 16); }
__device__ __forceinline__ u16 f2b(float f){
    u32 u = __float_as_uint(f);
    u32 r = (u + 0x7fffu + ((u >> 16) & 1u)) >> 16;
    return (u16)r;
}
__device__ __forceinline__ f32x4 mfma16(bf16x8 a, bf16x8 b, f32x4 c){
    return __builtin_amdgcn_mfma_f32_16x16x32_bf16(a, b, c, 0, 0, 0);
}

// ---------------- 1) conv_half (one batch): (62,H,W) f32 -> x31 NHWC f32 [pix][32]
__global__ void k_conv_half(const float* __restrict__ x, const float* __restrict__ w,
                            const float* __restrict__ bias, float* __restrict__ x31){
    __shared__ float sw[CH*CIN2];
    __shared__ float sb[CH+1];
    for(int i=threadIdx.x;i<CH*CIN2;i+=256) sw[i]=w[i];
    for(int i=threadIdx.x;i<CH;i+=256) sb[i]=bias[i];
    __syncthreads();
    int pix = blockIdx.x*256 + threadIdx.x;
    if(pix>=HW) return;
    float acc[CH];
    #pragma unroll
    for(int c=0;c<CH;c++) acc[c]=sb[c];
    for(int ci=0;ci<CIN2;ci++){
        float xv = x[(size_t)ci*HW + pix];
        #pragma unroll
        for(int c=0;c<CH;c++) acc[c] += sw[c*CIN2+ci]*xv;
    }
    float* o = x31 + (size_t)pix*32;
    #pragma unroll
    for(int c=0;c<CH;c++) o[c]=acc[c];
    o[31]=0.f;
}

// ---------------- 2) project: xp = clip(SRF @ x31, -1, 1), layout [3][HW] --------
__global__ void k_project(const float* __restrict__ x31, const float* __restrict__ srf,
                          float* __restrict__ xp){
    __shared__ float s[CM*CH];
    for(int i=threadIdx.x;i<CM*CH;i+=256) s[i]=srf[i];
    __syncthreads();
    int pix = blockIdx.x*256 + threadIdx.x;
    if(pix>=HW) return;
    const float* xr = x31 + (size_t)pix*32;
    #pragma unroll
    for(int m=0;m<CM;m++){
        float acc=0.f;
        #pragma unroll
        for(int c=0;c<CH;c++) acc += s[m*CH+c]*xr[c];
        acc = fminf(fmaxf(acc,-1.f),1.f);
        xp[(size_t)m*HW + pix] = acc;
    }
}

// ---------------- 3a) stats stage 1: per-chunk partial sums ------------------------
__global__ void k_stats1(const float* __restrict__ xp, const float* __restrict__ y,
                         float2* __restrict__ part){
    int bid = blockIdx.x;
    int p = bid >> 6, c = bid & 63;
    const float* src = (p<3) ? (xp + (size_t)p*HW) : (y + (size_t)(p-3)*HW);
    const float4* s4 = (const float4*)(src + c*1024);
    float4 v = s4[threadIdx.x];
    float s  = v.x + v.y + v.z + v.w;
    float ss = v.x*v.x + v.y*v.y + v.z*v.z + v.w*v.w;
    #pragma unroll
    for(int t=1;t<64;t<<=1){ s += __shfl_xor(s,t); ss += __shfl_xor(ss,t); }
    __shared__ float rs[4], rss[4];
    int wid = threadIdx.x>>6, lane = threadIdx.x&63;
    if(lane==0){ rs[wid]=s; rss[wid]=ss; }
    __syncthreads();
    if(threadIdx.x==0){
        part[bid] = float2{rs[0]+rs[1]+rs[2]+rs[3], rss[0]+rss[1]+rss[2]+rss[3]};
    }
}

// ---------------- 3b) stats stage 2: combine 64 partials -> mean/std(ddof=1) ------
__global__ void k_stats2(const float2* __restrict__ part, float* __restrict__ stats){
    int p = blockIdx.x;                 // 6 planes
    float2 pa = part[p*64 + threadIdx.x];
    float s = pa.x, ss = pa.y;
    #pragma unroll
    for(int t=1;t<64;t<<=1){ s += __shfl_xor(s,t); ss += __shfl_xor(ss,t); }
    if(threadIdx.x==0){
        float mean = s/(float)HW;
        float var = (ss - s*s/(float)HW) / (float)(HW-1);
        stats[p*2]   = mean;
        stats[p*2+1] = sqrtf(fmaxf(var,0.f));
    }
}

// ---------------- 4) align ---------------------------------------------------------
__global__ void k_align(const float* __restrict__ xp, const float* __restrict__ stats,
                        float* __restrict__ xa){
    int i = blockIdx.x*256 + threadIdx.x;
    if(i>=3*HW) return;
    int plane = i>>16;
    float sm = stats[plane*2], ssd = stats[plane*2+1];
    float rm = stats[(plane+3)*2], rsd = stats[(plane+3)*2+1];
    float v = (xp[i]-sm)/(ssd+1e-6f)*rsd + rm;
    xa[i] = fminf(fmaxf(v,-1.f),1.f);
}

// ---------------- 5) ssim horizontal gaussian pass ---------------------------------
__global__ void k_ssim_h(const float* __restrict__ xa, const float* __restrict__ y,
                         float* __restrict__ tmp){
    int i = blockIdx.x*256 + threadIdx.x;
    if(i>=3*HW) return;
    int plane = i>>16, hw = i&65535, h = hw>>8, w = hw&255;
    float g[9]; float gs=0.f;
    #pragma unroll
    for(int t=0;t<9;t++){ float cc=(float)(t-4); g[t]=expf(-cc*cc/4.5f); gs+=g[t]; }
    float inv = 1.f/gs;
    float s0=0,s1=0,s2=0,s3=0,s4=0;
    const float* xr = xa + (size_t)plane*HW + (size_t)h*256;
    const float* yr = y  + (size_t)plane*HW + (size_t)h*256;
    #pragma unroll
    for(int t=0;t<9;t++){
        int wc = w + t - 4;
        if(wc>=0 && wc<256){
            float gg = g[t]*inv;
            float a = xr[wc], b = yr[wc];
            s0+=gg*a; s1+=gg*b; s2+=gg*a*a; s3+=gg*b*b; s4+=gg*a*b;
        }
    }
    size_t base = (size_t)plane*5*HW + hw;
    tmp[base]=s0; tmp[base+HW]=s1; tmp[base+2*(size_t)HW]=s2; tmp[base+3*(size_t)HW]=s3; tmp[base+4*(size_t)HW]=s4;
}

// ---------------- 6) ssim vertical pass + difficulty -> diff, regin ch281 ---------
__global__ void k_ssim_v(const float* __restrict__ tmp, float* __restrict__ diff,
                         u16* __restrict__ regin){
    int pix = blockIdx.x*256 + threadIdx.x;
    if(pix>=HW) return;
    int h = pix>>8, w = pix&255;
    float g[9]; float gs=0.f;
    #pragma unroll
    for(int t=0;t<9;t++){ float cc=(float)(t-4); g[t]=expf(-cc*cc/4.5f); gs+=g[t]; }
    float inv = 1.f/gs;
    float msum = 0.f;
    for(int m=0;m<3;m++){
        float v0=0,v1=0,v2=0,v3=0,v4=0;
        #pragma unroll
        for(int t=0;t<9;t++){
            int hc = h + t - 4;
            if(hc>=0 && hc<256){
                float gg = g[t]*inv;
                size_t base = (size_t)m*5*HW + (size_t)hc*256 + w;
                v0+=gg*tmp[base]; v1+=gg*tmp[base+HW]; v2+=gg*tmp[base+2*(size_t)HW];
                v3+=gg*tmp[base+3*(size_t)HW]; v4+=gg*tmp[base+4*(size_t)HW];
            }
        }
        float mu1=v0, mu2=v1;
        float mu1s=mu1*mu1, mu2s=mu2*mu2, mu12=mu1*mu2;
        float sg1=v2-mu1s, sg2=v3-mu2s, sg12=v4-mu12;
        float num=(2.f*mu12+C1S)*(2.f*sg12+C2S);
        float den=(mu1s+mu2s+C1S)*(sg1+sg2+C2S);
        msum += num/den;
    }
    float ss = msum*(1.f/3.f);
    float d = fminf(fmaxf((1.f-ss)*0.5f,0.f),1.f);
    diff[pix] = d;
    regin[(size_t)pix*REGC + 281] = f2b(d);
}

// ---------------- 7) q,k 1x1 convs -> regin bf16 (32 px per block) ----------------
__global__ __launch_bounds__(128) void k_qk(const float* __restrict__ x31,
                     const float* __restrict__ y,
                     const float* __restrict__ qw, const float* __restrict__ qb,
                     const float* __restrict__ kw, const float* __restrict__ kb,
                     u16* __restrict__ regin){
    __shared__ float sqw[CE*CH];
    __shared__ float skw[CE*CM];
    __shared__ float sqb[CE], skb[CE];
    for(int i=threadIdx.x;i<CE*CH;i+=128) sqw[i]=qw[i];
    for(int i=threadIdx.x;i<CE*CM;i+=128) skw[i]=kw[i];
    if(threadIdx.x<CE){ sqb[threadIdx.x]=qb[threadIdx.x]; skb[threadIdx.x]=kb[threadIdx.x]; }
    __syncthreads();
    int co = threadIdx.x;
    int p0 = blockIdx.x*32;
    float wk0 = skw[co*CM+0], wk1 = skw[co*CM+1], wk2 = skw[co*CM+2];
    for(int pp=0;pp<32;pp++){
        int pix = p0+pp;
        const float* xr = x31 + (size_t)pix*32;   // block-uniform -> scalar loads
        float acc = sqb[co];
        #pragma unroll
        for(int c=0;c<CH;c++) acc += sqw[co*CH+c]*xr[c];
        u16* rg = regin + (size_t)pix*REGC;
        rg[co] = f2b(acc);
        float ack = skb[co] + wk0*y[pix] + wk1*y[HW+pix] + wk2*y[2*HW+pix];
        rg[128+co] = f2b(ack);
        if(co<6) rg[282+co] = 0;                  // zero channel pad
    }
}

// ---------------- 8) inverse l2 norms (lane-pair per pixel) ------------------------
__global__ __launch_bounds__(256) void k_norms(const u16* __restrict__ regin,
                                               float* __restrict__ qinv,
                                               float* __restrict__ kinv){
    int t = threadIdx.x;
    int half = t & 1, pidx = t >> 1;                // 128 px per block
    int pix = blockIdx.x*128 + pidx;
    const uint4* qp = (const uint4*)(regin + (size_t)pix*REGC) + half*8;
    const uint4* kp = (const uint4*)(regin + (size_t)pix*REGC + 128) + half*8;
    float sq = 0.f, sk = 0.f;
    #pragma unroll
    for(int i=0;i<8;i++){
        uint4 v = qp[i];
        sq += blo(v.x)*blo(v.x) + bhi(v.x)*bhi(v.x) + blo(v.y)*blo(v.y) + bhi(v.y)*bhi(v.y)
            + blo(v.z)*blo(v.z) + bhi(v.z)*bhi(v.z) + blo(v.w)*blo(v.w) + bhi(v.w)*bhi(v.w);
    }
    #pragma unroll
    for(int i=0;i<8;i++){
        uint4 v = kp[i];
        sk += blo(v.x)*blo(v.x) + bhi(v.x)*bhi(v.x) + blo(v.y)*blo(v.y) + bhi(v.y)*bhi(v.y)
            + blo(v.z)*blo(v.z) + bhi(v.z)*bhi(v.z) + blo(v.w)*blo(v.w) + bhi(v.w)*bhi(v.w);
    }
    sq += __shfl_xor(sq, 1);
    sk += __shfl_xor(sk, 1);
    if(half==0){
        qinv[pix] = 1.f/fmaxf(sqrtf(sq),1e-12f);
        kinv[pix] = 1.f/fmaxf(sqrtf(sk),1e-12f);
    }
}

// ---------------- 9) correlation volume: lane-pair per pixel ----------------------
__global__ __launch_bounds__(256) void k_corr(const u16* __restrict__ regin,
                                              const float* __restrict__ qinv,
                                              const float* __restrict__ kinv,
                                              u16* __restrict__ regout){
    int t = threadIdx.x;
    int half = t & 1, pidx = t >> 1;           // 128 pixels per block
    int bid = blockIdx.x;
    int tx = bid & 7, ty = bid >> 3;            // 8 x 64 grid
    int w = tx*32 + (pidx & 31);
    int h = ty*4 + (pidx >> 5);
    int pix = (h<<8) + w;

    uint4 q[8];
    const uint4* qp = (const uint4*)(regin + (size_t)pix*REGC) + half*8;
    #pragma unroll
    for(int i=0;i<8;i++) q[i] = qp[i];
    float qn = qinv[pix];

    #pragma unroll
    for(int dy=-2;dy<=2;dy++){
        int hc = min(max(h+dy,0),255);
        #pragma unroll
        for(int dx=-2;dx<=2;dx++){
            int wc = min(max(w+dx,0),255);
            int npix = (hc<<8)+wc;
            const uint4* kp = (const uint4*)(regin + (size_t)npix*REGC + 128) + half*8;
            float s = 0.f;
            #pragma unroll
            for(int i=0;i<8;i++){
                uint4 kv = kp[i];
                uint4 qv = q[i];
                s += blo(qv.x)*blo(kv.x) + bhi(qv.x)*bhi(kv.x);
                s += blo(qv.y)*blo(kv.y) + bhi(qv.y)*bhi(kv.y);
                s += blo(qv.z)*blo(kv.z) + bhi(qv.z)*bhi(kv.z);
                s += blo(qv.w)*blo(kv.w) + bhi(qv.w)*bhi(kv.w);
            }
            s += __shfl_xor(s, 1);              // merge channel halves
            int o = (dy+2)*5 + (dx+2);
            bool mine = half ? (o>=13) : (o<13);
            if(mine) regout[(size_t)pix*REGC + 256 + o] = f2b(s*qn*kinv[npix]);
        }
    }
}

// ---------------- 10) weight rearrange + zpad clear --------------------------------
__global__ void k_wre(const float* __restrict__ w1, const float* __restrict__ w2,
                      u16* __restrict__ w1f, u16* __restrict__ w2f,
                      u16* __restrict__ zpad){
    int i = blockIdx.x*256 + threadIdx.x;
    if(i < 32) zpad[i] = 0;                       // 64B zero source for halo DMA
    if(i < 9*9*128*32){
        int j = i & 7;
        int gg = (i>>3)&3;
        int co = (i>>5)&127;
        int rest = i>>12;          // tap*9 + kbg
        int kbg = rest%9, tap = rest/9;
        int ci = kbg*32 + gg*8 + j;
        float v = (ci<282) ? w1[((size_t)co*282 + ci)*9 + tap] : 0.f;
        w1f[i] = f2b(v);
    }
    if(i < 9*4*64*32){
        int j = i & 7;
        int gg = (i>>3)&3;
        int co = (i>>5)&63;
        int rest = i>>11;          // tap*4 + kbg
        int kbg = rest&3, tap = rest>>2;
        int ci = kbg*32 + gg*8 + j;
        w2f[i] = f2b(w2[((size_t)co*128 + ci)*9 + tap]);
    }
}

// ---------------- 11+12) MFMA 3x3 conv (implicit GEMM over taps) -------------------
__device__ __forceinline__ void lda4(const uint4* sbuf, int ky, int kx, int kb,
                                     int lane15, int lgrp, bf16x8* ar){
    #pragma unroll
    for(int mf=0;mf<4;mf++){
        int spx  = (mf&1)*16 + lane15 + kx;       // 0..33
        int srow = (mf>>1) + ky;                  // 0..3
        int slot = (srow*34 + spx)*8 + ((kb*4 + lgrp) ^ (spx&7));
        ar[mf] = *(const bf16x8*)&sbuf[slot];
    }
}

template<int NF, int KBGT, int NCO>
__device__ __forceinline__ void ldbN(const u16* __restrict__ wf, int kbg, int tap,
                                     int co0, int lane15, int lgrp, bf16x8* br){
    #pragma unroll
    for(int nf=0;nf<NF;nf++){
        size_t idx = ((size_t)((tap*KBGT + kbg)*NCO + co0 + nf*16 + lane15))*4 + lgrp;
        br[nf] = *(const bf16x8*)(wf + idx*8);
    }
}

template<int NF, int KBGT, int NCO, int KBI>
__device__ __forceinline__ void conv_steps(const uint4* sbuf, const u16* __restrict__ wf,
                                           int kbgbase, int co0, int lane15, int lgrp,
                                           f32x4 (&acc)[4][NF]){
    bf16x8 a[2][4];
    bf16x8 b[2][NF];
    lda4(sbuf, 0,0,0, lane15, lgrp, a[0]);
    ldbN<NF,KBGT,NCO>(wf, kbgbase, 0, co0, lane15, lgrp, b[0]);
    constexpr int NST = 9*KBI;
    #pragma unroll
    for(int s=0;s<NST;s++){
        int nx = s+1;
        if(nx < NST){
            int ky2,kx2,kb2;
            if(KBI==2){ ky2 = nx/6; kx2 = (nx>>1)%3; kb2 = nx&1; }
            else      { ky2 = nx/3; kx2 = nx%3;      kb2 = 0;   }
            lda4(sbuf, ky2,kx2,kb2, lane15, lgrp, a[nx&1]);
            ldbN<NF,KBGT,NCO>(wf, kbgbase+kb2, ky2*3+kx2, co0, lane15, lgrp, b[nx&1]);
        }
        #pragma unroll
        for(int mf=0;mf<4;mf++)
            #pragma unroll
            for(int nf=0;nf<NF;nf++)
                acc[mf][nf] = mfma16(a[s&1][mf], b[s&1][nf], acc[mf][nf]);
    }
}

template<int CSTRIDE, int CINTOT, int NCO, int KBGT, int NW>
__global__ __launch_bounds__(NW*64, 4) void k_conv3(const u16* __restrict__ in,
                                                    const u16* __restrict__ wf,
                                                    const float* __restrict__ bias,
                                                    u16* __restrict__ out,
                                                    const u16* __restrict__ zpad){
    constexpr int NF = NCO/(16*NW);
    constexpr int NCHUNK = (CINTOT + 63)/64;
    constexpr int NTH = NW*64;
    __shared__ uint4 sT[2*1088];
    int t = threadIdx.x;
    int lane15 = t & 15, lgrp = (t >> 4) & 3;
    int co0 = (t >> 6) * (NCO/NW);
    int bid = blockIdx.x;
    int tx = bid & 7, ty = bid >> 3;
    int row0 = ty*2, col0 = tx*32;

    f32x4 acc[4][NF];
    #pragma unroll
    for(int nf=0;nf<NF;nf++){
        float bsv = bias[co0 + nf*16 + lane15];
        #pragma unroll
        for(int mf=0;mf<4;mf++) acc[mf][nf] = f32x4{bsv,bsv,bsv,bsv};
    }

    auto stage = [&](int buf, int kc){
        constexpr int NIT = (1088 + NTH - 1)/NTH;
        #pragma unroll
        for(int it=0; it<NIT; ++it){
            int s = it*NTH + t;
            if(s >= 1088) continue;                   // whole-wave tail: safe
            int srow = s/272, rem = s - srow*272;
            int spx = rem>>3, ggp = rem&7;
            int gg = ggp ^ (spx&7);
            int gy = row0-1+srow, gx = col0-1+spx;
            bool ok = ((unsigned)gy<256u) && ((unsigned)gx<256u);
            const u16* src = ok ? (in + (size_t)((gy<<8)+gx)*CSTRIDE + kc + gg*8) : zpad;
            __builtin_amdgcn_global_load_lds(
                (const __attribute__((address_space(1))) u32*)src,
                (__attribute__((address_space(3))) u32*)&sT[buf*1088 + s],
                16, 0, 0);
        }
    };

    stage(0, 0);
    if(NW>1) __syncthreads();
    else     asm volatile("s_waitcnt vmcnt(0)" ::: "memory");

    int cur = 0;
    for(int j=0;j<NCHUNK;j++){
        if(j+1 < NCHUNK) stage(cur^1, (j+1)*64);
        if(CINTOT==288 && j==NCHUNK-1)
            conv_steps<NF,KBGT,NCO,1>(&sT[cur*1088], wf, j*2, co0, lane15, lgrp, acc);
        else
            conv_steps<NF,KBGT,NCO,2>(&sT[cur*1088], wf, j*2, co0, lane15, lgrp, acc);
        if(j+1 < NCHUNK){
            if(NW>1) __syncthreads();
            else     asm volatile("s_waitcnt vmcnt(0)" ::: "memory");
            cur ^= 1;
        }
    }

    #pragma unroll
    for(int mf=0;mf<4;mf++){
        int prow  = row0 + (mf>>1);
        int pcolb = col0 + (mf&1)*16 + lgrp*4;
        #pragma unroll
        for(int nf=0;nf<NF;nf++){
            int co = co0 + nf*16 + lane15;
            #pragma unroll
            for(int r=0;r<4;r++){
                int pix = (prow<<8) + pcolb + r;
                float v = acc[mf][nf][r];
                v = (v>0.f) ? v : 0.2f*v;
                out[(size_t)pix*NCO + co] = f2b(v);
            }
        }
    }
}

// ---------------- 13) flow (1x1 conv + tanh) + bilinear warp -----------------------
__device__ __forceinline__ float reflectc(float coord, float size){
    float c = fabsf(coord + 0.5f);
    float extra = fmodf(c, size);
    float flips = floorf(c/size);
    float fo = fmodf(flips, 2.0f);
    float r = (fo == 0.0f) ? (extra - 0.5f) : (size - extra - 0.5f);
    return fminf(fmaxf(r, 0.0f), size - 1.0f);
}

__global__ void k_flowwarp(const u16* __restrict__ h2, const float* __restrict__ w3,
                           const float* __restrict__ b3, const float* __restrict__ diff,
                           const float* __restrict__ x31, float* __restrict__ out){
    __shared__ float sw[130];
    for(int i=threadIdx.x;i<128;i+=256) sw[i]=w3[i];
    if(threadIdx.x<2) sw[128+threadIdx.x]=b3[threadIdx.x];
    __syncthreads();
    int pix = blockIdx.x*256 + threadIdx.x;
    if(pix>=HW) return;
    int h = pix>>8, w = pix&255;
    const uint4* h4 = (const uint4*)(h2 + (size_t)pix*64);
    float f0 = sw[128], f1 = sw[129];
    #pragma unroll
    for(int cc=0;cc<8;cc++){
        uint4 u = h4[cc];
        float vv[8] = {blo(u.x),bhi(u.x),blo(u.y),bhi(u.y),blo(u.z),bhi(u.z),blo(u.w),bhi(u.w)};
        #pragma unroll
        for(int j=0;j<8;j++){ int c = cc*8+j; f0 += sw[c]*vv[j]; f1 += sw[64+c]*vv[j]; }
    }
    float d = diff[pix];
    f0 = tanhf(f0)*2.0f*d;
    f1 = tanhf(f1)*2.0f*d;
    float ix = reflectc((float)w + f0, 256.f);
    float iy = reflectc((float)h + f1, 256.f);
    float x0 = floorf(ix), y0 = floorf(iy);
    float wx = ix-x0, wy = iy-y0;
    int x0i = min(max((int)x0,0),255);
    int x1i = min(x0i+1,255);
    int y0i = min(max((int)y0,0),255);
    int y1i = min(y0i+1,255);
    const float* p00 = x31 + ((size_t)((y0i<<8)+x0i))*32;
    const float* p01 = x31 + ((size_t)((y0i<<8)+x1i))*32;
    const float* p10 = x31 + ((size_t)((y1i<<8)+x0i))*32;
    const float* p11 = x31 + ((size_t)((y1i<<8)+x1i))*32;
    float w00=(1.f-wy)*(1.f-wx), w01=(1.f-wy)*wx, w10=wy*(1.f-wx), w11=wy*wx;
    float* ob = out + pix;
    #pragma unroll
    for(int c=0;c<CH;c++){
        ob[(size_t)c*HW] = w00*p00[c] + w01*p01[c] + w10*p10[c] + w11*p11[c];
    }
}

extern "C" void kernel_launch(void* const* d_in, const int* in_sizes, int n_in,
                              void* d_out, int out_size, void* d_ws, size_t ws_size,
                              hipStream_t stream) {
    const float* x    = (const float*)d_in[0];
    const float* y    = (const float*)d_in[1];
    const float* srf  = (const float*)d_in[2];
    const float* chw  = (const float*)d_in[3];
    const float* chb  = (const float*)d_in[4];
    const float* qw   = (const float*)d_in[5];
    const float* qb   = (const float*)d_in[6];
    const float* kw   = (const float*)d_in[7];
    const float* kb   = (const float*)d_in[8];
    const float* w1   = (const float*)d_in[9];
    const float* b1p  = (const float*)d_in[10];
    const float* w2   = (const float*)d_in[11];
    const float* b2p  = (const float*)d_in[12];
    const float* w3   = (const float*)d_in[13];
    const float* b3p  = (const float*)d_in[14];

    // Per-batch workspace (reused across b=0..3): ~78 MB total.
    char* ws = (char*)d_ws;
    size_t o = 0;
    float* x31   = (float*)(ws+o); o += (size_t)HW*32*4;       //  8.4 MB
    float* xp    = (float*)(ws+o); o += (size_t)3*HW*4;        //  0.8 MB
    float* xa    = (float*)(ws+o); o += (size_t)3*HW*4;        //  0.8 MB
    float* stats = (float*)(ws+o); o += 256;
    float2* part = (float2*)(ws+o);o += 384*sizeof(float2);
    float* tmp   = (float*)(ws+o); o += (size_t)15*HW*4;       //  3.9 MB
    float* diff  = (float*)(ws+o); o += (size_t)HW*4;          //  0.3 MB
    float* qinv  = (float*)(ws+o); o += (size_t)HW*4;
    float* kinv  = (float*)(ws+o); o += (size_t)HW*4;
    u16* regin   = (u16*)(ws+o);   o += (size_t)HW*REGC*2;     // 37.7 MB
    u16* h1      = (u16*)(ws+o);   o += (size_t)HW*128*2;      // 16.8 MB
    u16* h2      = (u16*)(ws+o);   o += (size_t)HW*64*2;       //  8.4 MB
    u16* w1f     = (u16*)(ws+o);   o += (size_t)9*9*128*32*2;  //  0.66 MB
    u16* w2f     = (u16*)(ws+o);   o += (size_t)9*4*64*32*2;   //  0.15 MB
    u16* zpad    = (u16*)(ws+o);   o += 64;                    //  64 B zero source

    k_wre<<<1296, 256, 0, stream>>>(w1, w2, w1f, w2f, zpad);

    for(int b=0;b<4;b++){
        const float* xb  = x + (size_t)b*CIN2*HW;
        const float* yb  = y + (size_t)b*CM*HW;
        float* outb      = (float*)d_out + (size_t)b*CH*HW;

        k_conv_half<<<256,  256, 0, stream>>>(xb, chw, chb, x31);
        k_project  <<<256,  256, 0, stream>>>(x31, srf, xp);
        k_stats1   <<<384,  256, 0, stream>>>(xp, yb, part);
        k_stats2   <<<6,     64, 0, stream>>>(part, stats);
        k_align    <<<768,  256, 0, stream>>>(xp, stats, xa);
        k_ssim_h   <<<768,  256, 0, stream>>>(xa, yb, tmp);
        k_ssim_v   <<<256,  256, 0, stream>>>(tmp, diff, regin);
        k_qk       <<<2048, 128, 0, stream>>>(x31, yb, qw, qb, kw, kb, regin);
        k_norms    <<<512,  256, 0, stream>>>(regin, qinv, kinv);
        k_corr     <<<512,  256, 0, stream>>>(regin, qinv, kinv, regin);
        k_conv3<288,288,128,9,4><<<1024, 256, 0, stream>>>(regin, w1f, b1p, h1, zpad);
        k_conv3<128,128, 64,4,2><<<1024, 128, 0, stream>>>(h1, w2f, b2p, h2, zpad);
        k_flowwarp <<<256,  256, 0, stream>>>(h2, w3, b3p, diff, x31, outb);
    }
}